// Round 15
// baseline (528.453 us; speedup 1.0000x reference)
//
#include <hip/hip_runtime.h>
#include <cstddef>
#include <cstdint>

#define NN 50000
#define NE 600000
#define H 128
#define NG 512
#define OUTC 128
#define EPSV 1e-5f
#define NB1 196    // ceil(NN/256)
#define MMB 1563   // ceil(NN/32)
#define CSRCAP 750016  // NE + 3*NN rounded up

typedef __attribute__((ext_vector_type(8))) short bf16x8;
typedef __attribute__((ext_vector_type(4))) float f32x4;

__device__ __forceinline__ unsigned short f2b(float f) {
  uint32_t u = __float_as_uint(f);
  uint32_t r = u + 0x7FFFu + ((u >> 16) & 1u);
  return (unsigned short)(r >> 16);
}
__device__ __forceinline__ float4 b4_to_f4(uint2 v) {
  float4 f;
  f.x = __uint_as_float(v.x << 16);
  f.y = __uint_as_float(v.x & 0xFFFF0000u);
  f.z = __uint_as_float(v.y << 16);
  f.w = __uint_as_float(v.y & 0xFFFF0000u);
  return f;
}
__device__ __forceinline__ uint2 f4_to_b4(float4 r) {
  uint2 o;
  o.x = (uint32_t)f2b(r.x) | ((uint32_t)f2b(r.y) << 16);
  o.y = (uint32_t)f2b(r.z) | ((uint32_t)f2b(r.w) << 16);
  return o;
}
// 8 bf16 (uint4) accumulate into 8 floats
__device__ __forceinline__ void b8_acc(uint4 v, float* a) {
  a[0] += __uint_as_float(v.x << 16);
  a[1] += __uint_as_float(v.x & 0xFFFF0000u);
  a[2] += __uint_as_float(v.y << 16);
  a[3] += __uint_as_float(v.y & 0xFFFF0000u);
  a[4] += __uint_as_float(v.z << 16);
  a[5] += __uint_as_float(v.z & 0xFFFF0000u);
  a[6] += __uint_as_float(v.w << 16);
  a[7] += __uint_as_float(v.w & 0xFFFF0000u);
}
__device__ __forceinline__ uint4 f8_pack(const float* a) {
  uint4 o;
  o.x = (uint32_t)f2b(a[0]) | ((uint32_t)f2b(a[1]) << 16);
  o.y = (uint32_t)f2b(a[2]) | ((uint32_t)f2b(a[3]) << 16);
  o.z = (uint32_t)f2b(a[4]) | ((uint32_t)f2b(a[5]) << 16);
  o.w = (uint32_t)f2b(a[6]) | ((uint32_t)f2b(a[7]) << 16);
  return o;
}

// ---- fp8 OCP e4m3 codec: HW cvt instructions when available, manual fallback ----
#if defined(__has_builtin)
#if __has_builtin(__builtin_amdgcn_cvt_f32_fp8) && __has_builtin(__builtin_amdgcn_cvt_pk_fp8_f32)
#define USE_HW_FP8 1
#endif
#endif

#ifdef USE_HW_FP8
__device__ __forceinline__ float4 f8x4_to_f4(uint32_t v) {
  float4 f;
  f.x = __builtin_amdgcn_cvt_f32_fp8(v, 0);
  f.y = __builtin_amdgcn_cvt_f32_fp8(v, 1);
  f.z = __builtin_amdgcn_cvt_f32_fp8(v, 2);
  f.w = __builtin_amdgcn_cvt_f32_fp8(v, 3);
  return f;
}
__device__ __forceinline__ uint32_t f4_to_f8x4(float4 f) {
  uint32_t w = 0;
  w = __builtin_amdgcn_cvt_pk_fp8_f32(f.x, f.y, w, false);
  w = __builtin_amdgcn_cvt_pk_fp8_f32(f.z, f.w, w, true);
  return w;
}
#else
__device__ __forceinline__ float e4m3_dec1(uint32_t v) {
  uint32_t s = (v & 0x80u) << 24;
  uint32_t e = (v >> 3) & 15u;
  uint32_t m = v & 7u;
  float f = e ? __uint_as_float(((e + 120u) << 23) | (m << 20))
              : (float)m * 0.001953125f;  // 2^-9
  return __uint_as_float(__float_as_uint(f) | s);
}
__device__ __forceinline__ float4 f8x4_to_f4(uint32_t v) {
  return make_float4(e4m3_dec1(v & 0xFF), e4m3_dec1((v >> 8) & 0xFF),
                     e4m3_dec1((v >> 16) & 0xFF), e4m3_dec1((v >> 24) & 0xFF));
}
__device__ __forceinline__ uint32_t e4m3_enc1(float x) {
  uint32_t s = (__float_as_uint(x) >> 24) & 0x80u;
  float ax = fabsf(x);
  if (!(ax > 0.f)) return s;
  if (ax >= 448.f) return s | 0x7Eu;
  if (ax < 0x1p-6f) {
    int m = (int)rintf(ax * 512.f);
    if (m > 7) return s | 0x08u;
    return s | (uint32_t)m;
  }
  uint32_t b = __float_as_uint(ax);
  int e = (int)(b >> 23) - 127;
  uint32_t man = b & 0x7FFFFFu;
  uint32_t keep = man >> 20;
  uint32_t rest = man & 0xFFFFFu;
  keep += (rest > 0x80000u) || (rest == 0x80000u && (keep & 1u));
  if (keep == 8u) { keep = 0u; e++; }
  if (e > 8) return s | 0x7Eu;
  return s | ((uint32_t)(e + 7) << 3) | keep;
}
__device__ __forceinline__ uint32_t f4_to_f8x4(float4 f) {
  return e4m3_enc1(f.x) | (e4m3_enc1(f.y) << 8) |
         (e4m3_enc1(f.z) << 16) | (e4m3_enc1(f.w) << 24);
}
#endif

// ---------------- combined init (+ W->bf16 W^T, + zero pad-rows) ----------------
__global__ void k_init(int* deg, int* cursor, float* stats,
                       float* vtsum0, float* vtsum1,
                       const float* __restrict__ vn_emb, float* vn,
                       const float* __restrict__ W, unsigned short* __restrict__ WT,
                       unsigned short* xb, unsigned short* bf0, unsigned short* bf1,
                       uint32_t* f8a, uint32_t* f8b) {
  int i = blockIdx.x * blockDim.x + threadIdx.x;
  if (i < NN) { deg[i] = 1; cursor[i] = 0; }
  if (i < 9 * 512) stats[i] = 0.f;
  if (i < 96) {  // zero row NN of the bf16 gather buffers
    int r = i >> 5, c = i & 31;
    unsigned short* bufs[3] = {xb, bf0, bf1};
    ((uint2*)bufs[r])[(size_t)NN * 32 + c] = make_uint2(0u, 0u);
  }
  if (i < 64) {  // zero row NN of the fp8 gather buffers
    int r = i >> 5, c = i & 31;
    uint32_t* bufs[2] = {f8a, f8b};
    bufs[r][(size_t)NN * 32 + c] = 0u;
  }
  if (i < 3 * H * H) {
    int l = i >> 14;
    int rem = i & 16383;
    int n = rem >> 7, k = rem & 127;
    WT[i] = f2b(W[l * H * H + k * H + n]);
  }
  if (i < NG * H) {
    vtsum0[i] = 0.f; vtsum1[i] = 0.f;
    vn[i] = vn_emb[i & (H - 1)];
  }
}

// merged: csr pad-fill + edge histogram + sorted-batch boundaries
__global__ void k_hist_fill(const int* __restrict__ dst, int* deg,
                            const int* __restrict__ batch, int* gstart, int* gend,
                            int* __restrict__ csr_src) {
  int i = blockIdx.x * blockDim.x + threadIdx.x;
  if (i < CSRCAP) csr_src[i] = NN;
  if (i < NE) atomicAdd(&deg[dst[i]], 1);
  if (i < NN) {
    int b = batch[i];
    if (i == 0 || batch[i - 1] != b) gstart[b] = i;
    if (i == NN - 1 || batch[i + 1] != b) gend[b] = i + 1;
  }
}

// scan phase 1 over PADDED counts P(d) = (deg[d]-1+3)&~3 ; also emits dinv
__global__ void k_scan1(const int* __restrict__ deg, int* bsum, float* dinv) {
  __shared__ int sh[256];
  int t = threadIdx.x;
  int i = blockIdx.x * 256 + t;
  int dv = (i < NN) ? deg[i] : 1;
  if (i < NN) dinv[i] = rsqrtf((float)dv);
  sh[t] = (i < NN) ? ((dv - 1 + 3) & ~3) : 0;
  __syncthreads();
  for (int o = 128; o > 0; o >>= 1) {
    if (t < o) sh[t] += sh[t + o];
    __syncthreads();
  }
  if (t == 0) bsum[blockIdx.x] = sh[0];
}
// scan3 with inlined scan2: each block computes its own prefix over bsum
__global__ void k_scan3(const int* __restrict__ deg, const int* __restrict__ bsum,
                        int* __restrict__ rowptr) {
  __shared__ int sh[256];
  __shared__ int pref[256];
  int t = threadIdx.x;
  int i = blockIdx.x * 256 + t;
  pref[t] = (t < NB1 && t < (int)blockIdx.x) ? bsum[t] : 0;
  __syncthreads();
  for (int o = 128; o > 0; o >>= 1) {
    if (t < o) pref[t] += pref[t + o];
    __syncthreads();
  }
  int boff = pref[0];
  int v = (i < NN) ? ((deg[i] - 1 + 3) & ~3) : 0;
  sh[t] = v;
  __syncthreads();
  for (int o = 1; o < 256; o <<= 1) {
    int u = (t >= o) ? sh[t - o] : 0;
    __syncthreads();
    sh[t] += u;
    __syncthreads();
  }
  if (i < NN) rowptr[i] = boff + sh[t] - v;
  if (i == NN - 1) rowptr[NN] = boff + sh[t];
}
// merged: csr scatter-fill + x -> u0 bf16 conversion
__global__ void k_fill_x(const int* __restrict__ src, const int* __restrict__ dst,
                         const int* __restrict__ rowptr, int* cursor,
                         int* __restrict__ csr_src,
                         const float* __restrict__ x, const float* __restrict__ dinv,
                         unsigned short* __restrict__ xb) {
  int i = blockIdx.x * blockDim.x + threadIdx.x;
  if (i < NE) {
    int s = src[i], d = dst[i];
    int pos = rowptr[d] + atomicAdd(&cursor[d], 1);
    csr_src[pos] = s;
  }
  if (i < NN * H / 4) {
    float dv = dinv[i >> 5];
    float4 v = ((const float4*)x)[i];
    v.x *= dv; v.y *= dv; v.z *= dv; v.w *= dv;
    ((uint2*)xb)[i] = f4_to_b4(v);
  }
}

// ---------------- fused conv: gather -> LDS -> MFMA + stats (bf16 Y) -------------------
// LDS diet: yt (16 rows f32) aliases abuf -> static LDS 12800B -> 5 blocks/CU (64KB window).
__global__ __launch_bounds__(256) void k_prop_mm(const unsigned short* __restrict__ U,
    const unsigned short* __restrict__ WT, const float* __restrict__ bias,
    unsigned short* __restrict__ Yb, float* __restrict__ pstat,
    const int* __restrict__ rowptr, const int* __restrict__ csr_src,
    const float* __restrict__ dinv) {
  __shared__ unsigned short abuf[32][136];   // 8704 B; aliased as yt[16][132] (8448 B)
  __shared__ float ps[4][H], pq[4][H];       // 4096 B
  float (*yt)[132] = (float (*)[132])abuf;
  int t = threadIdx.x;
  int lane32 = t & 31;
  int g = t >> 5;
  int sub = lane32 >> 4;   // which edge of the pair
  int l16 = lane32 & 15;   // col group (8 bf16 per lane)
  int rblk = blockIdx.x * 32;
  const uint4* u4 = (const uint4*)U;

  // phase 1: gather (lanes 0-15 edge e+2u, lanes 16-31 edge e+2u+1; uint4/lane)
  for (int rr = 0; rr < 4; rr++) {
    int d = rblk + g * 4 + rr;
    float a8[8] = {0.f, 0.f, 0.f, 0.f, 0.f, 0.f, 0.f, 0.f};
    float dv = 0.f;
    if (d < NN) {
      dv = dinv[d];
      if (sub == 0) b8_acc(u4[(size_t)d * 16 + l16], a8);   // self term
      int e = rowptr[d], e1 = rowptr[d + 1];
      for (; e + 7 < e1; e += 8) {
        int si[4]; uint4 gg[4];
#pragma unroll
        for (int u = 0; u < 4; u++) si[u] = csr_src[e + 2 * u + sub];
#pragma unroll
        for (int u = 0; u < 4; u++) gg[u] = u4[(size_t)si[u] * 16 + l16];
#pragma unroll
        for (int u = 0; u < 4; u++) b8_acc(gg[u], a8);
      }
      if (e < e1) {  // remainder exactly 4 (padded)
        int si0 = csr_src[e + sub];
        int si1 = csr_src[e + 2 + sub];
        uint4 g0 = u4[(size_t)si0 * 16 + l16];
        uint4 g1 = u4[(size_t)si1 * 16 + l16];
        b8_acc(g0, a8);
        b8_acc(g1, a8);
      }
    }
#pragma unroll
    for (int j = 0; j < 8; j++) a8[j] += __shfl_down(a8[j], 16, 32);
    if (sub == 0) {
#pragma unroll
      for (int j = 0; j < 8; j++) a8[j] *= dv;
      *(uint4*)&abuf[g * 4 + rr][l16 * 8] = f8_pack(a8);
    }
  }
  __syncthreads();

  // phase 2: MFMA
  int lane = t & 63;
  int wv = t >> 6;
  int wm = wv & 1, wn = wv >> 1;
  int col0 = wn * 64;
  int l15 = lane & 15;
  int quad = lane >> 4;
  f32x4 acc[4];
#pragma unroll
  for (int tt = 0; tt < 4; tt++) {
    float bb = bias[col0 + 16 * tt + l15];
    acc[tt][0] = bb; acc[tt][1] = bb; acc[tt][2] = bb; acc[tt][3] = bb;
  }
  const bf16x8* B0 = (const bf16x8*)(WT + (size_t)(col0 + l15) * H);
  const bf16x8* B1 = (const bf16x8*)(WT + (size_t)(col0 + 16 + l15) * H);
  const bf16x8* B2 = (const bf16x8*)(WT + (size_t)(col0 + 32 + l15) * H);
  const bf16x8* B3 = (const bf16x8*)(WT + (size_t)(col0 + 48 + l15) * H);
#pragma unroll
  for (int k0 = 0; k0 < 4; k0++) {
    bf16x8 a = *(const bf16x8*)&abuf[wm * 16 + l15][k0 * 32 + quad * 8];
    acc[0] = __builtin_amdgcn_mfma_f32_16x16x32_bf16(a, B0[k0 * 4 + quad], acc[0], 0, 0, 0);
    acc[1] = __builtin_amdgcn_mfma_f32_16x16x32_bf16(a, B1[k0 * 4 + quad], acc[1], 0, 0, 0);
    acc[2] = __builtin_amdgcn_mfma_f32_16x16x32_bf16(a, B2[k0 * 4 + quad], acc[2], 0, 0, 0);
    acc[3] = __builtin_amdgcn_mfma_f32_16x16x32_bf16(a, B3[k0 * 4 + quad], acc[3], 0, 0, 0);
  }

  // phase 3: two 16-row epilogue passes through the aliased yt tile
  int c4 = t & 31;
  float s0 = 0.f, s1 = 0.f, s2 = 0.f, s3 = 0.f;
  float q0 = 0.f, q1 = 0.f, q2 = 0.f, q3 = 0.f;
  for (int half = 0; half < 2; half++) {
    __syncthreads();   // abuf reads done (iter 0) / prev yt reads done (iter 1)
    if (wm == half) {
#pragma unroll
      for (int tt = 0; tt < 4; tt++) {
        int col = col0 + 16 * tt + l15;
#pragma unroll
        for (int r = 0; r < 4; r++) {
          yt[quad * 4 + r][col] = acc[tt][r];
        }
      }
    }
    __syncthreads();
#pragma unroll
    for (int i = 0; i < 2; i++) {
      int idx = t + i * 256;
      int row = idx >> 5;             // 0..15
      float4 v = *(const float4*)&yt[row][c4 * 4];
      int gr = rblk + half * 16 + row;
      if (gr < NN) {
        ((uint2*)Yb)[(size_t)gr * 32 + c4] = f4_to_b4(v);
        s0 += v.x; s1 += v.y; s2 += v.z; s3 += v.w;
        q0 += v.x * v.x; q1 += v.y * v.y; q2 += v.z * v.z; q3 += v.w * v.w;
      }
    }
  }
  s0 += __shfl_down(s0, 32, 64); s1 += __shfl_down(s1, 32, 64);
  s2 += __shfl_down(s2, 32, 64); s3 += __shfl_down(s3, 32, 64);
  q0 += __shfl_down(q0, 32, 64); q1 += __shfl_down(q1, 32, 64);
  q2 += __shfl_down(q2, 32, 64); q3 += __shfl_down(q3, 32, 64);
  if (lane < 32) {
    ps[wv][c4 * 4 + 0] = s0; ps[wv][c4 * 4 + 1] = s1;
    ps[wv][c4 * 4 + 2] = s2; ps[wv][c4 * 4 + 3] = s3;
    pq[wv][c4 * 4 + 0] = q0; pq[wv][c4 * 4 + 1] = q1;
    pq[wv][c4 * 4 + 2] = q2; pq[wv][c4 * 4 + 3] = q3;
  }
  __syncthreads();
  if (t < H) {
    pstat[(size_t)blockIdx.x * 256 + t] = ps[0][t] + ps[1][t] + ps[2][t] + ps[3][t];
    pstat[(size_t)blockIdx.x * 256 + 128 + t] = pq[0][t] + pq[1][t] + pq[2][t] + pq[3][t];
  }
}

__global__ void k_redstats(const float* __restrict__ pstat, float* __restrict__ gstats) {
  int t = threadIdx.x;
  float s = 0.f;
  for (int b = blockIdx.x; b < MMB; b += 32) s += pstat[(size_t)b * 256 + t];
  atomicAdd(&gstats[t], s);
}

// ---------------- fp8 APPNP propagation (unchanged) ----------
__global__ __launch_bounds__(256) void k_prop_f8(const uint32_t* __restrict__ U8,
    const unsigned short* __restrict__ baseb, uint32_t* __restrict__ out8,
    unsigned short* __restrict__ outb16,
    const int* __restrict__ rowptr, const int* __restrict__ csr_src,
    const float* __restrict__ dinv) {
  int lane = threadIdx.x & 31;
  int d = blockIdx.x * 8 + (threadIdx.x >> 5);
  float dv = dinv[d];
  size_t drow = (size_t)d * 32 + lane;
  float4 acc = f8x4_to_f4(U8[drow]);   // self term
  int e = rowptr[d], e1 = rowptr[d + 1];
  for (; e + 7 < e1; e += 8) {
    int si[8]; uint32_t gg[8];
#pragma unroll
    for (int u = 0; u < 8; u++) si[u] = csr_src[e + u];
#pragma unroll
    for (int u = 0; u < 8; u++) gg[u] = U8[(size_t)si[u] * 32 + lane];
#pragma unroll
    for (int u = 0; u < 8; u++) {
      float4 f = f8x4_to_f4(gg[u]);
      acc.x += f.x; acc.y += f.y; acc.z += f.z; acc.w += f.w;
    }
  }
  if (e < e1) {  // remainder exactly 4
    int si[4]; uint32_t gg[4];
#pragma unroll
    for (int u = 0; u < 4; u++) si[u] = csr_src[e + u];
#pragma unroll
    for (int u = 0; u < 4; u++) gg[u] = U8[(size_t)si[u] * 32 + lane];
#pragma unroll
    for (int u = 0; u < 4; u++) {
      float4 f = f8x4_to_f4(gg[u]);
      acc.x += f.x; acc.y += f.y; acc.z += f.z; acc.w += f.w;
    }
  }
  float4 bb = b4_to_f4(((const uint2*)baseb)[drow]);
  float k = 0.2f * dv;
  float4 h;
  h.x = k * acc.x + 0.8f * bb.x;
  h.y = k * acc.y + 0.8f * bb.y;
  h.z = k * acc.z + 0.8f * bb.z;
  h.w = k * acc.w + 0.8f * bb.w;
  if (out8) {
    float4 u = make_float4(h.x * dv, h.y * dv, h.z * dv, h.w * dv);
    out8[drow] = f4_to_f8x4(u);
  } else {
    ((uint2*)outb16)[drow] = f4_to_b4(h);
  }
}

// ---------------- BN+relu+vn add (8 rows/block) + segmented vt scatter -----
__global__ void k_bn_vn2(const unsigned short* __restrict__ Xb, const float* __restrict__ stats,
                         const float* __restrict__ g, const float* __restrict__ bt,
                         const float* __restrict__ vn, const int* __restrict__ batch,
                         const float* __restrict__ dinv,
                         unsigned short* __restrict__ outb, float* __restrict__ vtsum) {
  int c = threadIdx.x;
  int r0 = blockIdx.x * 8;
  int r1 = r0 + 8; if (r1 > NN) r1 = NN;
  const float invN = 1.0f / NN;
  float m = stats[c] * invN;
  float var = stats[H + c] * invN - m * m;
  float rs = rsqrtf(var + EPSV);
  float gc = g[c], bc = bt[c];
  int curb = batch[r0];
  float vnv = vn[curb * H + c];
  float s = 0.f;
  for (int r = r0; r < r1; r++) {
    int b = batch[r];
    if (b != curb) {
      atomicAdd(&vtsum[curb * H + c], s);
      s = 0.f; curb = b; vnv = vn[b * H + c];
    }
    float xv = __uint_as_float((uint32_t)Xb[(size_t)r * H + c] << 16);
    float y = fmaxf(gc * (xv - m) * rs + bc, 0.f) + vnv;
    outb[(size_t)r * H + c] = f2b(dinv[r] * y);
    s += y;
  }
  atomicAdd(&vtsum[curb * H + c], s);
}
// BN only (bf16 in), vectorized x4: baseb bf16 + u0 fp8
__global__ void k_bn_plain_b(const unsigned short* __restrict__ Xb, const float* __restrict__ stats,
                             const float* __restrict__ g, const float* __restrict__ bt,
                             const float* __restrict__ dinv,
                             unsigned short* __restrict__ baseb, uint32_t* __restrict__ out8) {
  int i = blockIdx.x * blockDim.x + threadIdx.x;
  if (i >= NN * H / 4) return;
  int c0 = (i * 4) & (H - 1);
  const float invN = 1.0f / NN;
  float4 v = b4_to_f4(((const uint2*)Xb)[i]);
  float4 y;
  {
    float m = stats[c0] * invN;
    float var = stats[H + c0] * invN - m * m;
    y.x = g[c0] * (v.x - m) * rsqrtf(var + EPSV) + bt[c0];
  }
  {
    float m = stats[c0 + 1] * invN;
    float var = stats[H + c0 + 1] * invN - m * m;
    y.y = g[c0 + 1] * (v.y - m) * rsqrtf(var + EPSV) + bt[c0 + 1];
  }
  {
    float m = stats[c0 + 2] * invN;
    float var = stats[H + c0 + 2] * invN - m * m;
    y.z = g[c0 + 2] * (v.z - m) * rsqrtf(var + EPSV) + bt[c0 + 2];
  }
  {
    float m = stats[c0 + 3] * invN;
    float var = stats[H + c0 + 3] * invN - m * m;
    y.w = g[c0 + 3] * (v.w - m) * rsqrtf(var + EPSV) + bt[c0 + 3];
  }
  ((uint2*)baseb)[i] = f4_to_b4(y);
  float dv = dinv[i >> 5];
  float4 u = make_float4(y.x * dv, y.y * dv, y.z * dv, y.w * dv);
  out8[i] = f4_to_f8x4(u);
}
__global__ void k_bn_addvn(const float* __restrict__ Y, const float* __restrict__ stats,
                           const float* __restrict__ g, const float* __restrict__ bt,
                           float* vn) {
  int idx = blockIdx.x * blockDim.x + threadIdx.x;
  if (idx >= NG * H) return;
  int c = idx & (H - 1);
  const float invN = 1.0f / NG;
  float m = stats[c] * invN;
  float var = stats[H + c] * invN - m * m;
  float rs = rsqrtf(var + EPSV);
  vn[idx] += fmaxf(g[c] * (Y[idx] - m) * rs + bt[c], 0.f);
}

// ---------------- small matmuls with fused stats ----------------
__global__ void k_mm_vn1(const float* __restrict__ vtsum, const float* __restrict__ vn,
                         const float* __restrict__ W, const float* __restrict__ bias,
                         float* __restrict__ Y, float* __restrict__ gstats) {
  __shared__ float xs[H];
  int r = blockIdx.x, c = threadIdx.x;
  if (c < H) xs[c] = vtsum[r * H + c] + vn[r * H + c];
  __syncthreads();
  float acc = bias[c];
#pragma unroll 16
  for (int k = 0; k < H; k++) acc += xs[k] * W[k * 256 + c];
  Y[r * 256 + c] = acc;
  atomicAdd(&gstats[c], acc);
  atomicAdd(&gstats[256 + c], acc * acc);
}
__global__ void k_mm_vn2(const float* __restrict__ t1raw, const float* __restrict__ stats1,
                         const float* __restrict__ g1, const float* __restrict__ bt1,
                         const float* __restrict__ W, const float* __restrict__ bias,
                         float* __restrict__ Y, float* __restrict__ gstats) {
  __shared__ float xs[256];
  int r = blockIdx.x, c = threadIdx.x;
  const float invG = 1.0f / NG;
#pragma unroll
  for (int hh = 0; hh < 2; hh++) {
    int cc = c + hh * 128;
    float m = stats1[cc] * invG;
    float var = stats1[256 + cc] * invG - m * m;
    float rs = rsqrtf(var + EPSV);
    xs[cc] = fmaxf(g1[cc] * (t1raw[r * 256 + cc] - m) * rs + bt1[cc], 0.f);
  }
  __syncthreads();
  float acc = bias[c];
#pragma unroll 16
  for (int k = 0; k < 256; k++) acc += xs[k] * W[k * H + c];
  Y[r * H + c] = acc;
  atomicAdd(&gstats[c], acc);
  atomicAdd(&gstats[H + c], acc * acc);
}

// ---------------- merged mean pool + head (256 thr: 2-way row-parallel pooling) --------
__global__ void k_pool_head(const unsigned short* __restrict__ hb,
                            const int* __restrict__ gstart, const int* __restrict__ gend,
                            const float* __restrict__ Wout, const float* __restrict__ bout,
                            float* __restrict__ out) {
  __shared__ float part[2][H];
  __shared__ float xs[H];
  int r = blockIdx.x;
  int t = threadIdx.x;
  int c = t & 127, pr = t >> 7;
  int s0 = gstart[r], s1 = gend[r];
  float s = 0.f;
  for (int row = s0 + pr; row < s1; row += 2)
    s += __uint_as_float((uint32_t)hb[(size_t)row * H + c] << 16);
  part[pr][c] = s;
  __syncthreads();
  if (t < H) {
    float cnt = (float)(s1 - s0);
    xs[t] = (part[0][t] + part[1][t]) / fmaxf(cnt, 1.f);
  }
  __syncthreads();
  if (t < OUTC) {
    float acc = bout[t];
#pragma unroll 16
    for (int k = 0; k < H; k++) acc += xs[k] * Wout[k * OUTC + t];
    out[r * OUTC + t] = acc;
  }
}

// ---------------- launch ----------------
extern "C" void kernel_launch(void* const* d_in, const int* in_sizes, int n_in,
                              void* d_out, int out_size, void* d_ws, size_t ws_size,
                              hipStream_t stream) {
  const float* x      = (const float*)d_in[0];
  const int*   ei     = (const int*)d_in[1];
  const int*   e_src  = ei;
  const int*   e_dst  = ei + NE;
  const int*   batch  = (const int*)d_in[2];
  const float* W      = (const float*)d_in[3];
  const float* b      = (const float*)d_in[4];
  const float* gamma  = (const float*)d_in[5];
  const float* beta   = (const float*)d_in[6];
  const float* vn_emb = (const float*)d_in[7];
  const float* W1     = (const float*)d_in[8];
  const float* b1     = (const float*)d_in[9];
  const float* g1     = (const float*)d_in[10];
  const float* bt1    = (const float*)d_in[11];
  const float* W2     = (const float*)d_in[12];
  const float* b2     = (const float*)d_in[13];
  const float* g2     = (const float*)d_in[14];
  const float* bt2    = (const float*)d_in[15];
  const float* Wout   = (const float*)d_in[16];
  const float* bout   = (const float*)d_in[17];
  float* out = (float*)d_out;

  char* p = (char*)d_ws;
  auto alloc = [&](size_t bytes) -> char* {
    char* r = p; p += (bytes + 255) & ~(size_t)255; return r;
  };
  float* hA       = (float*)alloc((size_t)NN * H * 4);        // carved: baseb bf16
  float* hB       = (float*)alloc((size_t)(NN + 1) * H * 4);  // carved: bf0/bf1 (+pad rows)
  float* hC       = (float*)alloc((size_t)NN * H * 2);        // bf16 conv output
  uint32_t* f8a   = (uint32_t*)alloc((size_t)(NN + 1) * H);   // fp8 APPNP ping
  uint32_t* f8b   = (uint32_t*)alloc((size_t)(NN + 1) * H);   // fp8 APPNP pong
  int*   deg      = (int*)alloc((size_t)NN * 4);
  int*   cursor   = (int*)alloc((size_t)NN * 4);
  int*   rowptr   = (int*)alloc((size_t)(NN + 1) * 4);
  int*   gstart   = (int*)alloc(512 * 4);
  int*   gend     = (int*)alloc(512 * 4);
  int*   csr_src  = (int*)alloc((size_t)CSRCAP * 4);
  float* dinv     = (float*)alloc((size_t)NN * 4);
  float* vn       = (float*)alloc((size_t)NG * H * 4);
  float* vtsum0   = (float*)alloc((size_t)NG * H * 4);
  float* vtsum1   = (float*)alloc((size_t)NG * H * 4);
  float* t1       = (float*)alloc((size_t)NG * 256 * 4);
  float* t2       = (float*)alloc((size_t)NG * H * 4);
  float* stats    = (float*)alloc(9 * 512 * 4);
  int*   bsum     = (int*)alloc(256 * 4);
  unsigned short* WT = (unsigned short*)alloc((size_t)3 * H * H * 2);
  unsigned short* xb = (unsigned short*)alloc((size_t)(NN + 1) * H * 2);
  float* pstat    = (float*)alloc((size_t)MMB * 256 * 4);

  unsigned short* bf0 = (unsigned short*)hB;                          // NN+1 rows
  unsigned short* bf1 = (unsigned short*)hB + (size_t)(NN + 1) * H;   // NN+1 rows
  unsigned short* baseb = (unsigned short*)hA;
  unsigned short* hCb = (unsigned short*)hC;

  const int B = 256;
  const int gV4   = (NN * H / 4 + B - 1) / B;   // 6250 (covers NE too)
  const int gVN   = (NG * H + B - 1) / B;
  const int gSEG  = (NN + 7) / 8;               // 6250
  const int gPROP = NN / 8;                     // 6250
  const int gPAD  = (CSRCAP + B - 1) / B;

  // ---- init + graph preprocessing ----
  k_init<<<(NG * H + B - 1) / B, B, 0, stream>>>(deg, cursor, stats, vtsum0, vtsum1,
                                                 vn_emb, vn, W, WT, xb, bf0, bf1, f8a, f8b);
  k_hist_fill<<<gPAD, B, 0, stream>>>(e_dst, deg, batch, gstart, gend, csr_src);
  k_scan1<<<NB1, 256, 0, stream>>>(deg, bsum, dinv);
  k_scan3<<<NB1, 256, 0, stream>>>(deg, bsum, rowptr);
  k_fill_x<<<gV4, B, 0, stream>>>(e_src, e_dst, rowptr, cursor, csr_src, x, dinv, xb);

  float* st[7];
  for (int i = 0; i < 7; i++) st[i] = stats + i * 512;

  // ---- conv layers 0,1 with virtual node MLP ----
  const unsigned short* curb = xb;
  unsigned short* bnout[2] = {bf1, bf0};
  float* vts[2] = {vtsum0, vtsum1};
  for (int i = 0; i < 2; i++) {
    int j = (i == 0) ? 1 : 0;
    k_prop_mm<<<MMB, 256, 0, stream>>>(curb, WT + (size_t)i * H * H, b + i * H, hCb, pstat,
                                       rowptr, csr_src, dinv);
    k_redstats<<<32, 256, 0, stream>>>(pstat, st[3 * i]);
    k_bn_vn2<<<gSEG, H, 0, stream>>>(hCb, st[3 * i], gamma + i * H, beta + i * H, vn, batch,
                                     dinv, bnout[i], vts[i]);
    k_mm_vn1<<<NG, 256, 0, stream>>>(vts[i], vn, W1 + (size_t)j * H * 256, b1 + j * 256, t1, st[3 * i + 1]);
    k_mm_vn2<<<NG, 128, 0, stream>>>(t1, st[3 * i + 1], g1 + j * 256, bt1 + j * 256,
                                     W2 + (size_t)j * 256 * H, b2 + j * H, t2, st[3 * i + 2]);
    k_bn_addvn<<<gVN, B, 0, stream>>>(t2, st[3 * i + 2], g2 + j * H, bt2 + j * H, vn);
    curb = bnout[i];
  }

  // ---- last conv layer: fused prop+mm (bf16 Y), BN -> baseb bf16 + u0 fp8 ----
  k_prop_mm<<<MMB, 256, 0, stream>>>(bf0, WT + (size_t)2 * H * H, b + 2 * H, hCb, pstat,
                                     rowptr, csr_src, dinv);
  k_redstats<<<32, 256, 0, stream>>>(pstat, st[6]);
  k_bn_plain_b<<<gV4, B, 0, stream>>>(hCb, st[6], gamma + 2 * H, beta + 2 * H, dinv, baseb, f8a);

  // ---- APPNP (4 props, fp8 iterate, bf16 base; final -> bf16 h in bf0) ----
  k_prop_f8<<<gPROP, 256, 0, stream>>>(f8a, baseb, f8b, nullptr, rowptr, csr_src, dinv);
  k_prop_f8<<<gPROP, 256, 0, stream>>>(f8b, baseb, f8a, nullptr, rowptr, csr_src, dinv);
  k_prop_f8<<<gPROP, 256, 0, stream>>>(f8a, baseb, f8b, nullptr, rowptr, csr_src, dinv);
  k_prop_f8<<<gPROP, 256, 0, stream>>>(f8b, baseb, nullptr, bf0, rowptr, csr_src, dinv);

  // ---- merged mean pool + head ----
  k_pool_head<<<NG, 256, 0, stream>>>(bf0, gstart, gend, Wout, bout, out);
}

// Round 16
// 505.685 us; speedup vs baseline: 1.0450x; 1.0450x over previous
//
#include <hip/hip_runtime.h>
#include <cstddef>
#include <cstdint>

#define NN 50000
#define NE 600000
#define H 128
#define NG 512
#define OUTC 128
#define EPSV 1e-5f
#define NB1 196    // ceil(NN/256)
#define MMB 1563   // ceil(NN/32)
#define CSRCAP 750016  // NE + 3*NN rounded up

typedef __attribute__((ext_vector_type(8))) short bf16x8;
typedef __attribute__((ext_vector_type(4))) float f32x4;

__device__ __forceinline__ unsigned short f2b(float f) {
  uint32_t u = __float_as_uint(f);
  uint32_t r = u + 0x7FFFu + ((u >> 16) & 1u);
  return (unsigned short)(r >> 16);
}
__device__ __forceinline__ float4 b4_to_f4(uint2 v) {
  float4 f;
  f.x = __uint_as_float(v.x << 16);
  f.y = __uint_as_float(v.x & 0xFFFF0000u);
  f.z = __uint_as_float(v.y << 16);
  f.w = __uint_as_float(v.y & 0xFFFF0000u);
  return f;
}
__device__ __forceinline__ uint2 f4_to_b4(float4 r) {
  uint2 o;
  o.x = (uint32_t)f2b(r.x) | ((uint32_t)f2b(r.y) << 16);
  o.y = (uint32_t)f2b(r.z) | ((uint32_t)f2b(r.w) << 16);
  return o;
}
// 8 bf16 (uint4) accumulate into 8 floats
__device__ __forceinline__ void b8_acc(uint4 v, float* a) {
  a[0] += __uint_as_float(v.x << 16);
  a[1] += __uint_as_float(v.x & 0xFFFF0000u);
  a[2] += __uint_as_float(v.y << 16);
  a[3] += __uint_as_float(v.y & 0xFFFF0000u);
  a[4] += __uint_as_float(v.z << 16);
  a[5] += __uint_as_float(v.z & 0xFFFF0000u);
  a[6] += __uint_as_float(v.w << 16);
  a[7] += __uint_as_float(v.w & 0xFFFF0000u);
}
__device__ __forceinline__ uint4 f8_pack(const float* a) {
  uint4 o;
  o.x = (uint32_t)f2b(a[0]) | ((uint32_t)f2b(a[1]) << 16);
  o.y = (uint32_t)f2b(a[2]) | ((uint32_t)f2b(a[3]) << 16);
  o.z = (uint32_t)f2b(a[4]) | ((uint32_t)f2b(a[5]) << 16);
  o.w = (uint32_t)f2b(a[6]) | ((uint32_t)f2b(a[7]) << 16);
  return o;
}

// ---- fp8 OCP e4m3 codec: HW cvt instructions when available, manual fallback ----
#if defined(__has_builtin)
#if __has_builtin(__builtin_amdgcn_cvt_f32_fp8) && __has_builtin(__builtin_amdgcn_cvt_pk_fp8_f32)
#define USE_HW_FP8 1
#endif
#endif

#ifdef USE_HW_FP8
__device__ __forceinline__ float4 f8x4_to_f4(uint32_t v) {
  float4 f;
  f.x = __builtin_amdgcn_cvt_f32_fp8(v, 0);
  f.y = __builtin_amdgcn_cvt_f32_fp8(v, 1);
  f.z = __builtin_amdgcn_cvt_f32_fp8(v, 2);
  f.w = __builtin_amdgcn_cvt_f32_fp8(v, 3);
  return f;
}
__device__ __forceinline__ uint32_t f4_to_f8x4(float4 f) {
  uint32_t w = 0;
  w = __builtin_amdgcn_cvt_pk_fp8_f32(f.x, f.y, w, false);
  w = __builtin_amdgcn_cvt_pk_fp8_f32(f.z, f.w, w, true);
  return w;
}
#else
__device__ __forceinline__ float e4m3_dec1(uint32_t v) {
  uint32_t s = (v & 0x80u) << 24;
  uint32_t e = (v >> 3) & 15u;
  uint32_t m = v & 7u;
  float f = e ? __uint_as_float(((e + 120u) << 23) | (m << 20))
              : (float)m * 0.001953125f;  // 2^-9
  return __uint_as_float(__float_as_uint(f) | s);
}
__device__ __forceinline__ float4 f8x4_to_f4(uint32_t v) {
  return make_float4(e4m3_dec1(v & 0xFF), e4m3_dec1((v >> 8) & 0xFF),
                     e4m3_dec1((v >> 16) & 0xFF), e4m3_dec1((v >> 24) & 0xFF));
}
__device__ __forceinline__ uint32_t e4m3_enc1(float x) {
  uint32_t s = (__float_as_uint(x) >> 24) & 0x80u;
  float ax = fabsf(x);
  if (!(ax > 0.f)) return s;
  if (ax >= 448.f) return s | 0x7Eu;
  if (ax < 0x1p-6f) {
    int m = (int)rintf(ax * 512.f);
    if (m > 7) return s | 0x08u;
    return s | (uint32_t)m;
  }
  uint32_t b = __float_as_uint(ax);
  int e = (int)(b >> 23) - 127;
  uint32_t man = b & 0x7FFFFFu;
  uint32_t keep = man >> 20;
  uint32_t rest = man & 0xFFFFFu;
  keep += (rest > 0x80000u) || (rest == 0x80000u && (keep & 1u));
  if (keep == 8u) { keep = 0u; e++; }
  if (e > 8) return s | 0x7Eu;
  return s | ((uint32_t)(e + 7) << 3) | keep;
}
__device__ __forceinline__ uint32_t f4_to_f8x4(float4 f) {
  return e4m3_enc1(f.x) | (e4m3_enc1(f.y) << 8) |
         (e4m3_enc1(f.z) << 16) | (e4m3_enc1(f.w) << 24);
}
#endif

// ---------------- combined init (+ W->bf16 W^T, + zero pad-rows) ----------------
__global__ void k_init(int* deg, int* cursor, float* stats,
                       float* vtsum0, float* vtsum1,
                       const float* __restrict__ vn_emb, float* vn,
                       const float* __restrict__ W, unsigned short* __restrict__ WT,
                       unsigned short* xb, unsigned short* bf0, unsigned short* bf1,
                       uint32_t* f8a, uint32_t* f8b) {
  int i = blockIdx.x * blockDim.x + threadIdx.x;
  if (i < NN) { deg[i] = 1; cursor[i] = 0; }
  if (i < 9 * 512) stats[i] = 0.f;
  if (i < 96) {  // zero row NN of the bf16 gather buffers
    int r = i >> 5, c = i & 31;
    unsigned short* bufs[3] = {xb, bf0, bf1};
    ((uint2*)bufs[r])[(size_t)NN * 32 + c] = make_uint2(0u, 0u);
  }
  if (i < 64) {  // zero row NN of the fp8 gather buffers
    int r = i >> 5, c = i & 31;
    uint32_t* bufs[2] = {f8a, f8b};
    bufs[r][(size_t)NN * 32 + c] = 0u;
  }
  if (i < 3 * H * H) {
    int l = i >> 14;
    int rem = i & 16383;
    int n = rem >> 7, k = rem & 127;
    WT[i] = f2b(W[l * H * H + k * H + n]);
  }
  if (i < NG * H) {
    vtsum0[i] = 0.f; vtsum1[i] = 0.f;
    vn[i] = vn_emb[i & (H - 1)];
  }
}

// edge histogram + sorted-batch boundaries (no pad-fill: pads written in scan3)
__global__ void k_hist_fill(const int* __restrict__ dst, int* deg,
                            const int* __restrict__ batch, int* gstart, int* gend) {
  int i = blockIdx.x * blockDim.x + threadIdx.x;
  if (i < NE) atomicAdd(&deg[dst[i]], 1);
  if (i < NN) {
    int b = batch[i];
    if (i == 0 || batch[i - 1] != b) gstart[b] = i;
    if (i == NN - 1 || batch[i + 1] != b) gend[b] = i + 1;
  }
}

// scan phase 1 over PADDED counts P(d) = (deg[d]-1+3)&~3 ; also emits dinv
__global__ void k_scan1(const int* __restrict__ deg, int* bsum, float* dinv) {
  __shared__ int sh[256];
  int t = threadIdx.x;
  int i = blockIdx.x * 256 + t;
  int dv = (i < NN) ? deg[i] : 1;
  if (i < NN) dinv[i] = rsqrtf((float)dv);
  sh[t] = (i < NN) ? ((dv - 1 + 3) & ~3) : 0;
  __syncthreads();
  for (int o = 128; o > 0; o >>= 1) {
    if (t < o) sh[t] += sh[t + o];
    __syncthreads();
  }
  if (t == 0) bsum[blockIdx.x] = sh[0];
}
// scan3 with inlined scan2; also writes the <=3 pad slots per node (csr_src = NN)
__global__ void k_scan3(const int* __restrict__ deg, const int* __restrict__ bsum,
                        int* __restrict__ rowptr, int* __restrict__ csr_src) {
  __shared__ int sh[256];
  __shared__ int pref[256];
  int t = threadIdx.x;
  int i = blockIdx.x * 256 + t;
  pref[t] = (t < NB1 && t < (int)blockIdx.x) ? bsum[t] : 0;
  __syncthreads();
  for (int o = 128; o > 0; o >>= 1) {
    if (t < o) pref[t] += pref[t + o];
    __syncthreads();
  }
  int boff = pref[0];
  int dgm1 = (i < NN) ? deg[i] - 1 : 0;
  int v = (dgm1 + 3) & ~3;
  sh[t] = v;
  __syncthreads();
  for (int o = 1; o < 256; o <<= 1) {
    int u = (t >= o) ? sh[t - o] : 0;
    __syncthreads();
    sh[t] += u;
    __syncthreads();
  }
  if (i < NN) {
    int rp = boff + sh[t] - v;
    rowptr[i] = rp;
    for (int pp = dgm1; pp < v; pp++) csr_src[rp + pp] = NN;  // pad slots
  }
  if (i == NN - 1) rowptr[NN] = boff + sh[t];
}
// merged: csr scatter-fill + x -> u0 bf16 conversion
__global__ void k_fill_x(const int* __restrict__ src, const int* __restrict__ dst,
                         const int* __restrict__ rowptr, int* cursor,
                         int* __restrict__ csr_src,
                         const float* __restrict__ x, const float* __restrict__ dinv,
                         unsigned short* __restrict__ xb) {
  int i = blockIdx.x * blockDim.x + threadIdx.x;
  if (i < NE) {
    int s = src[i], d = dst[i];
    int pos = rowptr[d] + atomicAdd(&cursor[d], 1);
    csr_src[pos] = s;
  }
  if (i < NN * H / 4) {
    float dv = dinv[i >> 5];
    float4 v = ((const float4*)x)[i];
    v.x *= dv; v.y *= dv; v.z *= dv; v.w *= dv;
    ((uint2*)xb)[i] = f4_to_b4(v);
  }
}

// ---------------- fused conv: gather -> LDS -> MFMA + stats (bf16 Y) -- R14 epilogue ----
__global__ __launch_bounds__(256) void k_prop_mm(const unsigned short* __restrict__ U,
    const unsigned short* __restrict__ WT, const float* __restrict__ bias,
    unsigned short* __restrict__ Yb, float* __restrict__ pstat,
    const int* __restrict__ rowptr, const int* __restrict__ csr_src,
    const float* __restrict__ dinv) {
  __shared__ char smem[32 * 132 * 4];   // union: abuf (bf16) / yt (f32)
  __shared__ float ps[4][H], pq[4][H];
  unsigned short (*abuf)[136] = (unsigned short (*)[136])smem;
  float (*yt)[132] = (float (*)[132])smem;
  int t = threadIdx.x;
  int lane32 = t & 31;
  int g = t >> 5;
  int sub = lane32 >> 4;   // which edge of the pair
  int l16 = lane32 & 15;   // col group (8 bf16 per lane)
  int rblk = blockIdx.x * 32;
  const uint4* u4 = (const uint4*)U;

  // phase 1: gather (lanes 0-15 edge e+2u, lanes 16-31 edge e+2u+1; uint4/lane)
  for (int rr = 0; rr < 4; rr++) {
    int d = rblk + g * 4 + rr;
    float a8[8] = {0.f, 0.f, 0.f, 0.f, 0.f, 0.f, 0.f, 0.f};
    float dv = 0.f;
    if (d < NN) {
      dv = dinv[d];
      if (sub == 0) b8_acc(u4[(size_t)d * 16 + l16], a8);   // self term
      int e = rowptr[d], e1 = rowptr[d + 1];
      for (; e + 7 < e1; e += 8) {
        int si[4]; uint4 gg[4];
#pragma unroll
        for (int u = 0; u < 4; u++) si[u] = csr_src[e + 2 * u + sub];
#pragma unroll
        for (int u = 0; u < 4; u++) gg[u] = u4[(size_t)si[u] * 16 + l16];
#pragma unroll
        for (int u = 0; u < 4; u++) b8_acc(gg[u], a8);
      }
      if (e < e1) {  // remainder exactly 4 (padded)
        int si0 = csr_src[e + sub];
        int si1 = csr_src[e + 2 + sub];
        uint4 g0 = u4[(size_t)si0 * 16 + l16];
        uint4 g1 = u4[(size_t)si1 * 16 + l16];
        b8_acc(g0, a8);
        b8_acc(g1, a8);
      }
    }
#pragma unroll
    for (int j = 0; j < 8; j++) a8[j] += __shfl_down(a8[j], 16, 32);
    if (sub == 0) {
#pragma unroll
      for (int j = 0; j < 8; j++) a8[j] *= dv;
      *(uint4*)&abuf[g * 4 + rr][l16 * 8] = f8_pack(a8);
    }
  }
  __syncthreads();

  // phase 2: MFMA
  int lane = t & 63;
  int wv = t >> 6;
  int wm = wv & 1, wn = wv >> 1;
  int col0 = wn * 64;
  int l15 = lane & 15;
  int quad = lane >> 4;
  f32x4 acc[4];
#pragma unroll
  for (int tt = 0; tt < 4; tt++) {
    float bb = bias[col0 + 16 * tt + l15];
    acc[tt][0] = bb; acc[tt][1] = bb; acc[tt][2] = bb; acc[tt][3] = bb;
  }
  const bf16x8* B0 = (const bf16x8*)(WT + (size_t)(col0 + l15) * H);
  const bf16x8* B1 = (const bf16x8*)(WT + (size_t)(col0 + 16 + l15) * H);
  const bf16x8* B2 = (const bf16x8*)(WT + (size_t)(col0 + 32 + l15) * H);
  const bf16x8* B3 = (const bf16x8*)(WT + (size_t)(col0 + 48 + l15) * H);
#pragma unroll
  for (int k0 = 0; k0 < 4; k0++) {
    bf16x8 a = *(const bf16x8*)&abuf[wm * 16 + l15][k0 * 32 + quad * 8];
    acc[0] = __builtin_amdgcn_mfma_f32_16x16x32_bf16(a, B0[k0 * 4 + quad], acc[0], 0, 0, 0);
    acc[1] = __builtin_amdgcn_mfma_f32_16x16x32_bf16(a, B1[k0 * 4 + quad], acc[1], 0, 0, 0);
    acc[2] = __builtin_amdgcn_mfma_f32_16x16x32_bf16(a, B2[k0 * 4 + quad], acc[2], 0, 0, 0);
    acc[3] = __builtin_amdgcn_mfma_f32_16x16x32_bf16(a, B3[k0 * 4 + quad], acc[3], 0, 0, 0);
  }
  __syncthreads();   // abuf dead; reuse as yt
#pragma unroll
  for (int tt = 0; tt < 4; tt++) {
    int col = col0 + 16 * tt + l15;
#pragma unroll
    for (int r = 0; r < 4; r++) {
      yt[wm * 16 + quad * 4 + r][col] = acc[tt][r];
    }
  }
  __syncthreads();
  int c4 = t & 31;
  float s0 = 0.f, s1 = 0.f, s2 = 0.f, s3 = 0.f;
  float q0 = 0.f, q1 = 0.f, q2 = 0.f, q3 = 0.f;
#pragma unroll
  for (int i = 0; i < 4; i++) {
    int idx = t + i * 256;
    int row = idx >> 5;
    float4 v = *(const float4*)&yt[row][c4 * 4];
    int gr = rblk + row;
    if (gr < NN) {
      ((uint2*)Yb)[(size_t)gr * 32 + c4] = f4_to_b4(v);
      s0 += v.x; s1 += v.y; s2 += v.z; s3 += v.w;
      q0 += v.x * v.x; q1 += v.y * v.y; q2 += v.z * v.z; q3 += v.w * v.w;
    }
  }
  s0 += __shfl_down(s0, 32, 64); s1 += __shfl_down(s1, 32, 64);
  s2 += __shfl_down(s2, 32, 64); s3 += __shfl_down(s3, 32, 64);
  q0 += __shfl_down(q0, 32, 64); q1 += __shfl_down(q1, 32, 64);
  q2 += __shfl_down(q2, 32, 64); q3 += __shfl_down(q3, 32, 64);
  if (lane < 32) {
    ps[wv][c4 * 4 + 0] = s0; ps[wv][c4 * 4 + 1] = s1;
    ps[wv][c4 * 4 + 2] = s2; ps[wv][c4 * 4 + 3] = s3;
    pq[wv][c4 * 4 + 0] = q0; pq[wv][c4 * 4 + 1] = q1;
    pq[wv][c4 * 4 + 2] = q2; pq[wv][c4 * 4 + 3] = q3;
  }
  __syncthreads();
  if (t < H) {
    pstat[(size_t)blockIdx.x * 256 + t] = ps[0][t] + ps[1][t] + ps[2][t] + ps[3][t];
    pstat[(size_t)blockIdx.x * 256 + 128 + t] = pq[0][t] + pq[1][t] + pq[2][t] + pq[3][t];
  }
}

__global__ void k_redstats(const float* __restrict__ pstat, float* __restrict__ gstats) {
  int t = threadIdx.x;
  float s = 0.f;
  for (int b = blockIdx.x; b < MMB; b += 32) s += pstat[(size_t)b * 256 + t];
  atomicAdd(&gstats[t], s);
}

// ---------------- fp8 APPNP propagation (unchanged) ----------
__global__ __launch_bounds__(256) void k_prop_f8(const uint32_t* __restrict__ U8,
    const unsigned short* __restrict__ baseb, uint32_t* __restrict__ out8,
    unsigned short* __restrict__ outb16,
    const int* __restrict__ rowptr, const int* __restrict__ csr_src,
    const float* __restrict__ dinv) {
  int lane = threadIdx.x & 31;
  int d = blockIdx.x * 8 + (threadIdx.x >> 5);
  float dv = dinv[d];
  size_t drow = (size_t)d * 32 + lane;
  float4 acc = f8x4_to_f4(U8[drow]);   // self term
  int e = rowptr[d], e1 = rowptr[d + 1];
  for (; e + 7 < e1; e += 8) {
    int si[8]; uint32_t gg[8];
#pragma unroll
    for (int u = 0; u < 8; u++) si[u] = csr_src[e + u];
#pragma unroll
    for (int u = 0; u < 8; u++) gg[u] = U8[(size_t)si[u] * 32 + lane];
#pragma unroll
    for (int u = 0; u < 8; u++) {
      float4 f = f8x4_to_f4(gg[u]);
      acc.x += f.x; acc.y += f.y; acc.z += f.z; acc.w += f.w;
    }
  }
  if (e < e1) {  // remainder exactly 4
    int si[4]; uint32_t gg[4];
#pragma unroll
    for (int u = 0; u < 4; u++) si[u] = csr_src[e + u];
#pragma unroll
    for (int u = 0; u < 4; u++) gg[u] = U8[(size_t)si[u] * 32 + lane];
#pragma unroll
    for (int u = 0; u < 4; u++) {
      float4 f = f8x4_to_f4(gg[u]);
      acc.x += f.x; acc.y += f.y; acc.z += f.z; acc.w += f.w;
    }
  }
  float4 bb = b4_to_f4(((const uint2*)baseb)[drow]);
  float k = 0.2f * dv;
  float4 h;
  h.x = k * acc.x + 0.8f * bb.x;
  h.y = k * acc.y + 0.8f * bb.y;
  h.z = k * acc.z + 0.8f * bb.z;
  h.w = k * acc.w + 0.8f * bb.w;
  if (out8) {
    float4 u = make_float4(h.x * dv, h.y * dv, h.z * dv, h.w * dv);
    out8[drow] = f4_to_f8x4(u);
  } else {
    ((uint2*)outb16)[drow] = f4_to_b4(h);
  }
}

// ---------------- BN+relu+vn add (8 rows/block) + segmented vt scatter -----
__global__ void k_bn_vn2(const unsigned short* __restrict__ Xb, const float* __restrict__ stats,
                         const float* __restrict__ g, const float* __restrict__ bt,
                         const float* __restrict__ vn, const int* __restrict__ batch,
                         const float* __restrict__ dinv,
                         unsigned short* __restrict__ outb, float* __restrict__ vtsum) {
  int c = threadIdx.x;
  int r0 = blockIdx.x * 8;
  int r1 = r0 + 8; if (r1 > NN) r1 = NN;
  const float invN = 1.0f / NN;
  float m = stats[c] * invN;
  float var = stats[H + c] * invN - m * m;
  float rs = rsqrtf(var + EPSV);
  float gc = g[c], bc = bt[c];
  int curb = batch[r0];
  float vnv = vn[curb * H + c];
  float s = 0.f;
  for (int r = r0; r < r1; r++) {
    int b = batch[r];
    if (b != curb) {
      atomicAdd(&vtsum[curb * H + c], s);
      s = 0.f; curb = b; vnv = vn[b * H + c];
    }
    float xv = __uint_as_float((uint32_t)Xb[(size_t)r * H + c] << 16);
    float y = fmaxf(gc * (xv - m) * rs + bc, 0.f) + vnv;
    outb[(size_t)r * H + c] = f2b(dinv[r] * y);
    s += y;
  }
  atomicAdd(&vtsum[curb * H + c], s);
}
// BN only (bf16 in), vectorized x4: baseb bf16 + u0 fp8
__global__ void k_bn_plain_b(const unsigned short* __restrict__ Xb, const float* __restrict__ stats,
                             const float* __restrict__ g, const float* __restrict__ bt,
                             const float* __restrict__ dinv,
                             unsigned short* __restrict__ baseb, uint32_t* __restrict__ out8) {
  int i = blockIdx.x * blockDim.x + threadIdx.x;
  if (i >= NN * H / 4) return;
  int c0 = (i * 4) & (H - 1);
  const float invN = 1.0f / NN;
  float4 v = b4_to_f4(((const uint2*)Xb)[i]);
  float4 y;
  {
    float m = stats[c0] * invN;
    float var = stats[H + c0] * invN - m * m;
    y.x = g[c0] * (v.x - m) * rsqrtf(var + EPSV) + bt[c0];
  }
  {
    float m = stats[c0 + 1] * invN;
    float var = stats[H + c0 + 1] * invN - m * m;
    y.y = g[c0 + 1] * (v.y - m) * rsqrtf(var + EPSV) + bt[c0 + 1];
  }
  {
    float m = stats[c0 + 2] * invN;
    float var = stats[H + c0 + 2] * invN - m * m;
    y.z = g[c0 + 2] * (v.z - m) * rsqrtf(var + EPSV) + bt[c0 + 2];
  }
  {
    float m = stats[c0 + 3] * invN;
    float var = stats[H + c0 + 3] * invN - m * m;
    y.w = g[c0 + 3] * (v.w - m) * rsqrtf(var + EPSV) + bt[c0 + 3];
  }
  ((uint2*)baseb)[i] = f4_to_b4(y);
  float dv = dinv[i >> 5];
  float4 u = make_float4(y.x * dv, y.y * dv, y.z * dv, y.w * dv);
  out8[i] = f4_to_f8x4(u);
}
__global__ void k_bn_addvn(const float* __restrict__ Y, const float* __restrict__ stats,
                           const float* __restrict__ g, const float* __restrict__ bt,
                           float* vn) {
  int idx = blockIdx.x * blockDim.x + threadIdx.x;
  if (idx >= NG * H) return;
  int c = idx & (H - 1);
  const float invN = 1.0f / NG;
  float m = stats[c] * invN;
  float var = stats[H + c] * invN - m * m;
  float rs = rsqrtf(var + EPSV);
  vn[idx] += fmaxf(g[c] * (Y[idx] - m) * rs + bt[c], 0.f);
}

// ---------------- small matmuls with fused stats ----------------
__global__ void k_mm_vn1(const float* __restrict__ vtsum, const float* __restrict__ vn,
                         const float* __restrict__ W, const float* __restrict__ bias,
                         float* __restrict__ Y, float* __restrict__ gstats) {
  __shared__ float xs[H];
  int r = blockIdx.x, c = threadIdx.x;
  if (c < H) xs[c] = vtsum[r * H + c] + vn[r * H + c];
  __syncthreads();
  float acc = bias[c];
#pragma unroll 16
  for (int k = 0; k < H; k++) acc += xs[k] * W[k * 256 + c];
  Y[r * 256 + c] = acc;
  atomicAdd(&gstats[c], acc);
  atomicAdd(&gstats[256 + c], acc * acc);
}
__global__ void k_mm_vn2(const float* __restrict__ t1raw, const float* __restrict__ stats1,
                         const float* __restrict__ g1, const float* __restrict__ bt1,
                         const float* __restrict__ W, const float* __restrict__ bias,
                         float* __restrict__ Y, float* __restrict__ gstats) {
  __shared__ float xs[256];
  int r = blockIdx.x, c = threadIdx.x;
  const float invG = 1.0f / NG;
#pragma unroll
  for (int hh = 0; hh < 2; hh++) {
    int cc = c + hh * 128;
    float m = stats1[cc] * invG;
    float var = stats1[256 + cc] * invG - m * m;
    float rs = rsqrtf(var + EPSV);
    xs[cc] = fmaxf(g1[cc] * (t1raw[r * 256 + cc] - m) * rs + bt1[cc], 0.f);
  }
  __syncthreads();
  float acc = bias[c];
#pragma unroll 16
  for (int k = 0; k < 256; k++) acc += xs[k] * W[k * H + c];
  Y[r * H + c] = acc;
  atomicAdd(&gstats[c], acc);
  atomicAdd(&gstats[H + c], acc * acc);
}

// ---------------- merged mean pool + head (256 thr: 2-way row-parallel pooling) --------
__global__ void k_pool_head(const unsigned short* __restrict__ hb,
                            const int* __restrict__ gstart, const int* __restrict__ gend,
                            const float* __restrict__ Wout, const float* __restrict__ bout,
                            float* __restrict__ out) {
  __shared__ float part[2][H];
  __shared__ float xs[H];
  int r = blockIdx.x;
  int t = threadIdx.x;
  int c = t & 127, pr = t >> 7;
  int s0 = gstart[r], s1 = gend[r];
  float s = 0.f;
  for (int row = s0 + pr; row < s1; row += 2)
    s += __uint_as_float((uint32_t)hb[(size_t)row * H + c] << 16);
  part[pr][c] = s;
  __syncthreads();
  if (t < H) {
    float cnt = (float)(s1 - s0);
    xs[t] = (part[0][t] + part[1][t]) / fmaxf(cnt, 1.f);
  }
  __syncthreads();
  if (t < OUTC) {
    float acc = bout[t];
#pragma unroll 16
    for (int k = 0; k < H; k++) acc += xs[k] * Wout[k * OUTC + t];
    out[r * OUTC + t] = acc;
  }
}

// ---------------- launch ----------------
extern "C" void kernel_launch(void* const* d_in, const int* in_sizes, int n_in,
                              void* d_out, int out_size, void* d_ws, size_t ws_size,
                              hipStream_t stream) {
  const float* x      = (const float*)d_in[0];
  const int*   ei     = (const int*)d_in[1];
  const int*   e_src  = ei;
  const int*   e_dst  = ei + NE;
  const int*   batch  = (const int*)d_in[2];
  const float* W      = (const float*)d_in[3];
  const float* b      = (const float*)d_in[4];
  const float* gamma  = (const float*)d_in[5];
  const float* beta   = (const float*)d_in[6];
  const float* vn_emb = (const float*)d_in[7];
  const float* W1     = (const float*)d_in[8];
  const float* b1     = (const float*)d_in[9];
  const float* g1     = (const float*)d_in[10];
  const float* bt1    = (const float*)d_in[11];
  const float* W2     = (const float*)d_in[12];
  const float* b2     = (const float*)d_in[13];
  const float* g2     = (const float*)d_in[14];
  const float* bt2    = (const float*)d_in[15];
  const float* Wout   = (const float*)d_in[16];
  const float* bout   = (const float*)d_in[17];
  float* out = (float*)d_out;

  char* p = (char*)d_ws;
  auto alloc = [&](size_t bytes) -> char* {
    char* r = p; p += (bytes + 255) & ~(size_t)255; return r;
  };
  float* hA       = (float*)alloc((size_t)NN * H * 4);        // carved: baseb bf16
  float* hB       = (float*)alloc((size_t)(NN + 1) * H * 4);  // carved: bf0/bf1 (+pad rows)
  float* hC       = (float*)alloc((size_t)NN * H * 2);        // bf16 conv output
  uint32_t* f8a   = (uint32_t*)alloc((size_t)(NN + 1) * H);   // fp8 APPNP ping
  uint32_t* f8b   = (uint32_t*)alloc((size_t)(NN + 1) * H);   // fp8 APPNP pong
  int*   deg      = (int*)alloc((size_t)NN * 4);
  int*   cursor   = (int*)alloc((size_t)NN * 4);
  int*   rowptr   = (int*)alloc((size_t)(NN + 1) * 4);
  int*   gstart   = (int*)alloc(512 * 4);
  int*   gend     = (int*)alloc(512 * 4);
  int*   csr_src  = (int*)alloc((size_t)CSRCAP * 4);
  float* dinv     = (float*)alloc((size_t)NN * 4);
  float* vn       = (float*)alloc((size_t)NG * H * 4);
  float* vtsum0   = (float*)alloc((size_t)NG * H * 4);
  float* vtsum1   = (float*)alloc((size_t)NG * H * 4);
  float* t1       = (float*)alloc((size_t)NG * 256 * 4);
  float* t2       = (float*)alloc((size_t)NG * H * 4);
  float* stats    = (float*)alloc(9 * 512 * 4);
  int*   bsum     = (int*)alloc(256 * 4);
  unsigned short* WT = (unsigned short*)alloc((size_t)3 * H * H * 2);
  unsigned short* xb = (unsigned short*)alloc((size_t)(NN + 1) * H * 2);
  float* pstat    = (float*)alloc((size_t)MMB * 256 * 4);

  unsigned short* bf0 = (unsigned short*)hB;                          // NN+1 rows
  unsigned short* bf1 = (unsigned short*)hB + (size_t)(NN + 1) * H;   // NN+1 rows
  unsigned short* baseb = (unsigned short*)hA;
  unsigned short* hCb = (unsigned short*)hC;

  const int B = 256;
  const int gV4   = (NN * H / 4 + B - 1) / B;   // 6250 (covers NE too)
  const int gVN   = (NG * H + B - 1) / B;
  const int gSEG  = (NN + 7) / 8;               // 6250
  const int gPROP = NN / 8;                     // 6250
  const int gNE   = (NE + B - 1) / B;           // 2344 (covers NN too)

  // ---- init + graph preprocessing ----
  k_init<<<(NG * H + B - 1) / B, B, 0, stream>>>(deg, cursor, stats, vtsum0, vtsum1,
                                                 vn_emb, vn, W, WT, xb, bf0, bf1, f8a, f8b);
  k_hist_fill<<<gNE, B, 0, stream>>>(e_dst, deg, batch, gstart, gend);
  k_scan1<<<NB1, 256, 0, stream>>>(deg, bsum, dinv);
  k_scan3<<<NB1, 256, 0, stream>>>(deg, bsum, rowptr, csr_src);
  k_fill_x<<<gV4, B, 0, stream>>>(e_src, e_dst, rowptr, cursor, csr_src, x, dinv, xb);

  float* st[7];
  for (int i = 0; i < 7; i++) st[i] = stats + i * 512;

  // ---- conv layers 0,1 with virtual node MLP ----
  const unsigned short* curb = xb;
  unsigned short* bnout[2] = {bf1, bf0};
  float* vts[2] = {vtsum0, vtsum1};
  for (int i = 0; i < 2; i++) {
    int j = (i == 0) ? 1 : 0;
    k_prop_mm<<<MMB, 256, 0, stream>>>(curb, WT + (size_t)i * H * H, b + i * H, hCb, pstat,
                                       rowptr, csr_src, dinv);
    k_redstats<<<32, 256, 0, stream>>>(pstat, st[3 * i]);
    k_bn_vn2<<<gSEG, H, 0, stream>>>(hCb, st[3 * i], gamma + i * H, beta + i * H, vn, batch,
                                     dinv, bnout[i], vts[i]);
    k_mm_vn1<<<NG, 256, 0, stream>>>(vts[i], vn, W1 + (size_t)j * H * 256, b1 + j * 256, t1, st[3 * i + 1]);
    k_mm_vn2<<<NG, 128, 0, stream>>>(t1, st[3 * i + 1], g1 + j * 256, bt1 + j * 256,
                                     W2 + (size_t)j * 256 * H, b2 + j * H, t2, st[3 * i + 2]);
    k_bn_addvn<<<gVN, B, 0, stream>>>(t2, st[3 * i + 2], g2 + j * H, bt2 + j * H, vn);
    curb = bnout[i];
  }

  // ---- last conv layer: fused prop+mm (bf16 Y), BN -> baseb bf16 + u0 fp8 ----
  k_prop_mm<<<MMB, 256, 0, stream>>>(bf0, WT + (size_t)2 * H * H, b + 2 * H, hCb, pstat,
                                     rowptr, csr_src, dinv);
  k_redstats<<<32, 256, 0, stream>>>(pstat, st[6]);
  k_bn_plain_b<<<gV4, B, 0, stream>>>(hCb, st[6], gamma + 2 * H, beta + 2 * H, dinv, baseb, f8a);

  // ---- APPNP (4 props, fp8 iterate, bf16 base; final -> bf16 h in bf0) ----
  k_prop_f8<<<gPROP, 256, 0, stream>>>(f8a, baseb, f8b, nullptr, rowptr, csr_src, dinv);
  k_prop_f8<<<gPROP, 256, 0, stream>>>(f8b, baseb, f8a, nullptr, rowptr, csr_src, dinv);
  k_prop_f8<<<gPROP, 256, 0, stream>>>(f8a, baseb, f8b, nullptr, rowptr, csr_src, dinv);
  k_prop_f8<<<gPROP, 256, 0, stream>>>(f8b, baseb, nullptr, bf0, rowptr, csr_src, dinv);

  // ---- merged mean pool + head ----
  k_pool_head<<<NG, 256, 0, stream>>>(bf0, gstart, gend, Wout, bout, out);
}

// Round 17
// 470.184 us; speedup vs baseline: 1.1239x; 1.0755x over previous
//
#include <hip/hip_runtime.h>
#include <cstddef>
#include <cstdint>

#define NN 50000
#define NE 600000
#define H 128
#define NG 512
#define OUTC 128
#define EPSV 1e-5f
#define NB1 196    // ceil(NN/256)
#define MMB 1563   // ceil(NN/32)
#define CSRCAP 750016  // NE + 3*NN rounded up

typedef __attribute__((ext_vector_type(8))) short bf16x8;
typedef __attribute__((ext_vector_type(4))) float f32x4;

__device__ __forceinline__ unsigned short f2b(float f) {
  uint32_t u = __float_as_uint(f);
  uint32_t r = u + 0x7FFFu + ((u >> 16) & 1u);
  return (unsigned short)(r >> 16);
}
__device__ __forceinline__ float4 b4_to_f4(uint2 v) {
  float4 f;
  f.x = __uint_as_float(v.x << 16);
  f.y = __uint_as_float(v.x & 0xFFFF0000u);
  f.z = __uint_as_float(v.y << 16);
  f.w = __uint_as_float(v.y & 0xFFFF0000u);
  return f;
}
__device__ __forceinline__ uint2 f4_to_b4(float4 r) {
  uint2 o;
  o.x = (uint32_t)f2b(r.x) | ((uint32_t)f2b(r.y) << 16);
  o.y = (uint32_t)f2b(r.z) | ((uint32_t)f2b(r.w) << 16);
  return o;
}
// 8 bf16 (uint4) accumulate into 8 floats
__device__ __forceinline__ void b8_acc(uint4 v, float* a) {
  a[0] += __uint_as_float(v.x << 16);
  a[1] += __uint_as_float(v.x & 0xFFFF0000u);
  a[2] += __uint_as_float(v.y << 16);
  a[3] += __uint_as_float(v.y & 0xFFFF0000u);
  a[4] += __uint_as_float(v.z << 16);
  a[5] += __uint_as_float(v.z & 0xFFFF0000u);
  a[6] += __uint_as_float(v.w << 16);
  a[7] += __uint_as_float(v.w & 0xFFFF0000u);
}
__device__ __forceinline__ uint4 f8_pack(const float* a) {
  uint4 o;
  o.x = (uint32_t)f2b(a[0]) | ((uint32_t)f2b(a[1]) << 16);
  o.y = (uint32_t)f2b(a[2]) | ((uint32_t)f2b(a[3]) << 16);
  o.z = (uint32_t)f2b(a[4]) | ((uint32_t)f2b(a[5]) << 16);
  o.w = (uint32_t)f2b(a[6]) | ((uint32_t)f2b(a[7]) << 16);
  return o;
}

// ---- fp8 OCP e4m3 codec: HW cvt instructions when available, manual fallback ----
#if defined(__has_builtin)
#if __has_builtin(__builtin_amdgcn_cvt_f32_fp8) && __has_builtin(__builtin_amdgcn_cvt_pk_fp8_f32)
#define USE_HW_FP8 1
#endif
#endif

#ifdef USE_HW_FP8
__device__ __forceinline__ float4 f8x4_to_f4(uint32_t v) {
  float4 f;
  f.x = __builtin_amdgcn_cvt_f32_fp8(v, 0);
  f.y = __builtin_amdgcn_cvt_f32_fp8(v, 1);
  f.z = __builtin_amdgcn_cvt_f32_fp8(v, 2);
  f.w = __builtin_amdgcn_cvt_f32_fp8(v, 3);
  return f;
}
__device__ __forceinline__ uint32_t f4_to_f8x4(float4 f) {
  uint32_t w = 0;
  w = __builtin_amdgcn_cvt_pk_fp8_f32(f.x, f.y, w, false);
  w = __builtin_amdgcn_cvt_pk_fp8_f32(f.z, f.w, w, true);
  return w;
}
#else
__device__ __forceinline__ float e4m3_dec1(uint32_t v) {
  uint32_t s = (v & 0x80u) << 24;
  uint32_t e = (v >> 3) & 15u;
  uint32_t m = v & 7u;
  float f = e ? __uint_as_float(((e + 120u) << 23) | (m << 20))
              : (float)m * 0.001953125f;  // 2^-9
  return __uint_as_float(__float_as_uint(f) | s);
}
__device__ __forceinline__ float4 f8x4_to_f4(uint32_t v) {
  return make_float4(e4m3_dec1(v & 0xFF), e4m3_dec1((v >> 8) & 0xFF),
                     e4m3_dec1((v >> 16) & 0xFF), e4m3_dec1((v >> 24) & 0xFF));
}
__device__ __forceinline__ uint32_t e4m3_enc1(float x) {
  uint32_t s = (__float_as_uint(x) >> 24) & 0x80u;
  float ax = fabsf(x);
  if (!(ax > 0.f)) return s;
  if (ax >= 448.f) return s | 0x7Eu;
  if (ax < 0x1p-6f) {
    int m = (int)rintf(ax * 512.f);
    if (m > 7) return s | 0x08u;
    return s | (uint32_t)m;
  }
  uint32_t b = __float_as_uint(ax);
  int e = (int)(b >> 23) - 127;
  uint32_t man = b & 0x7FFFFFu;
  uint32_t keep = man >> 20;
  uint32_t rest = man & 0xFFFFFu;
  keep += (rest > 0x80000u) || (rest == 0x80000u && (keep & 1u));
  if (keep == 8u) { keep = 0u; e++; }
  if (e > 8) return s | 0x7Eu;
  return s | ((uint32_t)(e + 7) << 3) | keep;
}
__device__ __forceinline__ uint32_t f4_to_f8x4(float4 f) {
  return e4m3_enc1(f.x) | (e4m3_enc1(f.y) << 8) |
         (e4m3_enc1(f.z) << 16) | (e4m3_enc1(f.w) << 24);
}
#endif

// ---------------- combined init (+ W->bf16 W^T, + zero pad-rows) ----------------
__global__ void k_init(int* deg, int* cursor, float* stats,
                       float* vtsum0,
                       const float* __restrict__ vn_emb, float* vn,
                       const float* __restrict__ W, unsigned short* __restrict__ WT,
                       unsigned short* xb, unsigned short* bf0, unsigned short* bf1,
                       uint32_t* f8a, uint32_t* f8b) {
  int i = blockIdx.x * blockDim.x + threadIdx.x;
  if (i < NN) { deg[i] = 1; cursor[i] = 0; }
  if (i < 9 * 512) stats[i] = 0.f;
  if (i < 96) {  // zero row NN of the bf16 gather buffers
    int r = i >> 5, c = i & 31;
    unsigned short* bufs[3] = {xb, bf0, bf1};
    ((uint2*)bufs[r])[(size_t)NN * 32 + c] = make_uint2(0u, 0u);
  }
  if (i < 64) {  // zero row NN of the fp8 gather buffers
    int r = i >> 5, c = i & 31;
    uint32_t* bufs[2] = {f8a, f8b};
    bufs[r][(size_t)NN * 32 + c] = 0u;
  }
  if (i < 3 * H * H) {
    int l = i >> 14;
    int rem = i & 16383;
    int n = rem >> 7, k = rem & 127;
    WT[i] = f2b(W[l * H * H + k * H + n]);
  }
  if (i < NG * H) {
    vtsum0[i] = 0.f;
    vn[i] = vn_emb[i & (H - 1)];
  }
}

// edge histogram + sorted-batch boundaries (no pad-fill: pads written in scan3)
__global__ void k_hist_fill(const int* __restrict__ dst, int* deg,
                            const int* __restrict__ batch, int* gstart, int* gend) {
  int i = blockIdx.x * blockDim.x + threadIdx.x;
  if (i < NE) atomicAdd(&deg[dst[i]], 1);
  if (i < NN) {
    int b = batch[i];
    if (i == 0 || batch[i - 1] != b) gstart[b] = i;
    if (i == NN - 1 || batch[i + 1] != b) gend[b] = i + 1;
  }
}

// scan phase 1 over PADDED counts P(d) = (deg[d]-1+3)&~3 ; also emits dinv
__global__ void k_scan1(const int* __restrict__ deg, int* bsum, float* dinv) {
  __shared__ int sh[256];
  int t = threadIdx.x;
  int i = blockIdx.x * 256 + t;
  int dv = (i < NN) ? deg[i] : 1;
  if (i < NN) dinv[i] = rsqrtf((float)dv);
  sh[t] = (i < NN) ? ((dv - 1 + 3) & ~3) : 0;
  __syncthreads();
  for (int o = 128; o > 0; o >>= 1) {
    if (t < o) sh[t] += sh[t + o];
    __syncthreads();
  }
  if (t == 0) bsum[blockIdx.x] = sh[0];
}
// scan3 with inlined scan2; also writes the <=3 pad slots per node (csr_src = NN)
__global__ void k_scan3(const int* __restrict__ deg, const int* __restrict__ bsum,
                        int* __restrict__ rowptr, int* __restrict__ csr_src) {
  __shared__ int sh[256];
  __shared__ int pref[256];
  int t = threadIdx.x;
  int i = blockIdx.x * 256 + t;
  pref[t] = (t < NB1 && t < (int)blockIdx.x) ? bsum[t] : 0;
  __syncthreads();
  for (int o = 128; o > 0; o >>= 1) {
    if (t < o) pref[t] += pref[t + o];
    __syncthreads();
  }
  int boff = pref[0];
  int dgm1 = (i < NN) ? deg[i] - 1 : 0;
  int v = (dgm1 + 3) & ~3;
  sh[t] = v;
  __syncthreads();
  for (int o = 1; o < 256; o <<= 1) {
    int u = (t >= o) ? sh[t - o] : 0;
    __syncthreads();
    sh[t] += u;
    __syncthreads();
  }
  if (i < NN) {
    int rp = boff + sh[t] - v;
    rowptr[i] = rp;
    for (int pp = dgm1; pp < v; pp++) csr_src[rp + pp] = NN;  // pad slots
  }
  if (i == NN - 1) rowptr[NN] = boff + sh[t];
}
// merged: csr scatter-fill + x -> u0 bf16 conversion
__global__ void k_fill_x(const int* __restrict__ src, const int* __restrict__ dst,
                         const int* __restrict__ rowptr, int* cursor,
                         int* __restrict__ csr_src,
                         const float* __restrict__ x, const float* __restrict__ dinv,
                         unsigned short* __restrict__ xb) {
  int i = blockIdx.x * blockDim.x + threadIdx.x;
  if (i < NE) {
    int s = src[i], d = dst[i];
    int pos = rowptr[d] + atomicAdd(&cursor[d], 1);
    csr_src[pos] = s;
  }
  if (i < NN * H / 4) {
    float dv = dinv[i >> 5];
    float4 v = ((const float4*)x)[i];
    v.x *= dv; v.y *= dv; v.z *= dv; v.w *= dv;
    ((uint2*)xb)[i] = f4_to_b4(v);
  }
}

// ---------------- fused conv: gather -> LDS -> MFMA + stats (bf16 Y) -------------------
__global__ __launch_bounds__(256) void k_prop_mm(const unsigned short* __restrict__ U,
    const unsigned short* __restrict__ WT, const float* __restrict__ bias,
    unsigned short* __restrict__ Yb, float* __restrict__ pstat,
    const int* __restrict__ rowptr, const int* __restrict__ csr_src,
    const float* __restrict__ dinv) {
  __shared__ char smem[32 * 132 * 4];   // union: abuf (bf16) / yt (f32)
  __shared__ float ps[4][H], pq[4][H];
  unsigned short (*abuf)[136] = (unsigned short (*)[136])smem;
  float (*yt)[132] = (float (*)[132])smem;
  int t = threadIdx.x;
  int lane32 = t & 31;
  int g = t >> 5;
  int sub = lane32 >> 4;   // which edge of the pair
  int l16 = lane32 & 15;   // col group (8 bf16 per lane)
  int rblk = blockIdx.x * 32;
  const uint4* u4 = (const uint4*)U;

  // phase 1: gather (lanes 0-15 edge e+2u, lanes 16-31 edge e+2u+1; uint4/lane)
  for (int rr = 0; rr < 4; rr++) {
    int d = rblk + g * 4 + rr;
    float a8[8] = {0.f, 0.f, 0.f, 0.f, 0.f, 0.f, 0.f, 0.f};
    float dv = 0.f;
    if (d < NN) {
      dv = dinv[d];
      if (sub == 0) b8_acc(u4[(size_t)d * 16 + l16], a8);   // self term
      int e = rowptr[d], e1 = rowptr[d + 1];
      for (; e + 7 < e1; e += 8) {
        int si[4]; uint4 gg[4];
#pragma unroll
        for (int u = 0; u < 4; u++) si[u] = csr_src[e + 2 * u + sub];
#pragma unroll
        for (int u = 0; u < 4; u++) gg[u] = u4[(size_t)si[u] * 16 + l16];
#pragma unroll
        for (int u = 0; u < 4; u++) b8_acc(gg[u], a8);
      }
      if (e < e1) {  // remainder exactly 4 (padded)
        int si0 = csr_src[e + sub];
        int si1 = csr_src[e + 2 + sub];
        uint4 g0 = u4[(size_t)si0 * 16 + l16];
        uint4 g1 = u4[(size_t)si1 * 16 + l16];
        b8_acc(g0, a8);
        b8_acc(g1, a8);
      }
    }
#pragma unroll
    for (int j = 0; j < 8; j++) a8[j] += __shfl_down(a8[j], 16, 32);
    if (sub == 0) {
#pragma unroll
      for (int j = 0; j < 8; j++) a8[j] *= dv;
      *(uint4*)&abuf[g * 4 + rr][l16 * 8] = f8_pack(a8);
    }
  }
  __syncthreads();

  // phase 2: MFMA
  int lane = t & 63;
  int wv = t >> 6;
  int wm = wv & 1, wn = wv >> 1;
  int col0 = wn * 64;
  int l15 = lane & 15;
  int quad = lane >> 4;
  f32x4 acc[4];
#pragma unroll
  for (int tt = 0; tt < 4; tt++) {
    float bb = bias[col0 + 16 * tt + l15];
    acc[tt][0] = bb; acc[tt][1] = bb; acc[tt][2] = bb; acc[tt][3] = bb;
  }
  const bf16x8* B0 = (const bf16x8*)(WT + (size_t)(col0 + l15) * H);
  const bf16x8* B1 = (const bf16x8*)(WT + (size_t)(col0 + 16 + l15) * H);
  const bf16x8* B2 = (const bf16x8*)(WT + (size_t)(col0 + 32 + l15) * H);
  const bf16x8* B3 = (const bf16x8*)(WT + (size_t)(col0 + 48 + l15) * H);
#pragma unroll
  for (int k0 = 0; k0 < 4; k0++) {
    bf16x8 a = *(const bf16x8*)&abuf[wm * 16 + l15][k0 * 32 + quad * 8];
    acc[0] = __builtin_amdgcn_mfma_f32_16x16x32_bf16(a, B0[k0 * 4 + quad], acc[0], 0, 0, 0);
    acc[1] = __builtin_amdgcn_mfma_f32_16x16x32_bf16(a, B1[k0 * 4 + quad], acc[1], 0, 0, 0);
    acc[2] = __builtin_amdgcn_mfma_f32_16x16x32_bf16(a, B2[k0 * 4 + quad], acc[2], 0, 0, 0);
    acc[3] = __builtin_amdgcn_mfma_f32_16x16x32_bf16(a, B3[k0 * 4 + quad], acc[3], 0, 0, 0);
  }
  __syncthreads();   // abuf dead; reuse as yt
#pragma unroll
  for (int tt = 0; tt < 4; tt++) {
    int col = col0 + 16 * tt + l15;
#pragma unroll
    for (int r = 0; r < 4; r++) {
      yt[wm * 16 + quad * 4 + r][col] = acc[tt][r];
    }
  }
  __syncthreads();
  int c4 = t & 31;
  float s0 = 0.f, s1 = 0.f, s2 = 0.f, s3 = 0.f;
  float q0 = 0.f, q1 = 0.f, q2 = 0.f, q3 = 0.f;
#pragma unroll
  for (int i = 0; i < 4; i++) {
    int idx = t + i * 256;
    int row = idx >> 5;
    float4 v = *(const float4*)&yt[row][c4 * 4];
    int gr = rblk + row;
    if (gr < NN) {
      ((uint2*)Yb)[(size_t)gr * 32 + c4] = f4_to_b4(v);
      s0 += v.x; s1 += v.y; s2 += v.z; s3 += v.w;
      q0 += v.x * v.x; q1 += v.y * v.y; q2 += v.z * v.z; q3 += v.w * v.w;
    }
  }
  s0 += __shfl_down(s0, 32, 64); s1 += __shfl_down(s1, 32, 64);
  s2 += __shfl_down(s2, 32, 64); s3 += __shfl_down(s3, 32, 64);
  q0 += __shfl_down(q0, 32, 64); q1 += __shfl_down(q1, 32, 64);
  q2 += __shfl_down(q2, 32, 64); q3 += __shfl_down(q3, 32, 64);
  if (lane < 32) {
    ps[wv][c4 * 4 + 0] = s0; ps[wv][c4 * 4 + 1] = s1;
    ps[wv][c4 * 4 + 2] = s2; ps[wv][c4 * 4 + 3] = s3;
    pq[wv][c4 * 4 + 0] = q0; pq[wv][c4 * 4 + 1] = q1;
    pq[wv][c4 * 4 + 2] = q2; pq[wv][c4 * 4 + 3] = q3;
  }
  __syncthreads();
  if (t < H) {
    pstat[(size_t)blockIdx.x * 256 + t] = ps[0][t] + ps[1][t] + ps[2][t] + ps[3][t];
    pstat[(size_t)blockIdx.x * 256 + 128 + t] = pq[0][t] + pq[1][t] + pq[2][t] + pq[3][t];
  }
}

__global__ void k_redstats(const float* __restrict__ pstat, float* __restrict__ gstats) {
  int t = threadIdx.x;
  float s = 0.f;
  for (int b = blockIdx.x; b < MMB; b += 32) s += pstat[(size_t)b * 256 + t];
  atomicAdd(&gstats[t], s);
}

// ---------------- fp8 APPNP propagation ----------
__global__ __launch_bounds__(256) void k_prop_f8(const uint32_t* __restrict__ U8,
    const unsigned short* __restrict__ baseb, uint32_t* __restrict__ out8,
    unsigned short* __restrict__ outb16,
    const int* __restrict__ rowptr, const int* __restrict__ csr_src,
    const float* __restrict__ dinv) {
  int lane = threadIdx.x & 31;
  int d = blockIdx.x * 8 + (threadIdx.x >> 5);
  float dv = dinv[d];
  size_t drow = (size_t)d * 32 + lane;
  float4 acc = f8x4_to_f4(U8[drow]);   // self term
  int e = rowptr[d], e1 = rowptr[d + 1];
  for (; e + 7 < e1; e += 8) {
    int si[8]; uint32_t gg[8];
#pragma unroll
    for (int u = 0; u < 8; u++) si[u] = csr_src[e + u];
#pragma unroll
    for (int u = 0; u < 8; u++) gg[u] = U8[(size_t)si[u] * 32 + lane];
#pragma unroll
    for (int u = 0; u < 8; u++) {
      float4 f = f8x4_to_f4(gg[u]);
      acc.x += f.x; acc.y += f.y; acc.z += f.z; acc.w += f.w;
    }
  }
  if (e < e1) {  // remainder exactly 4
    int si[4]; uint32_t gg[4];
#pragma unroll
    for (int u = 0; u < 4; u++) si[u] = csr_src[e + u];
#pragma unroll
    for (int u = 0; u < 4; u++) gg[u] = U8[(size_t)si[u] * 32 + lane];
#pragma unroll
    for (int u = 0; u < 4; u++) {
      float4 f = f8x4_to_f4(gg[u]);
      acc.x += f.x; acc.y += f.y; acc.z += f.z; acc.w += f.w;
    }
  }
  float4 bb = b4_to_f4(((const uint2*)baseb)[drow]);
  float k = 0.2f * dv;
  float4 h;
  h.x = k * acc.x + 0.8f * bb.x;
  h.y = k * acc.y + 0.8f * bb.y;
  h.z = k * acc.z + 0.8f * bb.z;
  h.w = k * acc.w + 0.8f * bb.w;
  if (out8) {
    float4 u = make_float4(h.x * dv, h.y * dv, h.z * dv, h.w * dv);
    out8[drow] = f4_to_f8x4(u);
  } else {
    ((uint2*)outb16)[drow] = f4_to_b4(h);
  }
}

// ---------------- BN+relu+vn add (8 rows/block); vtsum scatter optional -----
__global__ void k_bn_vn2(const unsigned short* __restrict__ Xb, const float* __restrict__ stats,
                         const float* __restrict__ g, const float* __restrict__ bt,
                         const float* __restrict__ vn, const int* __restrict__ batch,
                         const float* __restrict__ dinv,
                         unsigned short* __restrict__ outb, float* __restrict__ vtsum) {
  int c = threadIdx.x;
  int r0 = blockIdx.x * 8;
  int r1 = r0 + 8; if (r1 > NN) r1 = NN;
  const float invN = 1.0f / NN;
  float m = stats[c] * invN;
  float var = stats[H + c] * invN - m * m;
  float rs = rsqrtf(var + EPSV);
  float gc = g[c], bc = bt[c];
  int curb = batch[r0];
  float vnv = vn[curb * H + c];
  float s = 0.f;
  for (int r = r0; r < r1; r++) {
    int b = batch[r];
    if (b != curb) {
      if (vtsum) atomicAdd(&vtsum[curb * H + c], s);
      s = 0.f; curb = b; vnv = vn[b * H + c];
    }
    float xv = __uint_as_float((uint32_t)Xb[(size_t)r * H + c] << 16);
    float y = fmaxf(gc * (xv - m) * rs + bc, 0.f) + vnv;
    outb[(size_t)r * H + c] = f2b(dinv[r] * y);
    if (vtsum) s += y;
  }
  if (vtsum) atomicAdd(&vtsum[curb * H + c], s);
}
// BN only (bf16 in), vectorized x4: baseb bf16 + u0 fp8
__global__ void k_bn_plain_b(const unsigned short* __restrict__ Xb, const float* __restrict__ stats,
                             const float* __restrict__ g, const float* __restrict__ bt,
                             const float* __restrict__ dinv,
                             unsigned short* __restrict__ baseb, uint32_t* __restrict__ out8) {
  int i = blockIdx.x * blockDim.x + threadIdx.x;
  if (i >= NN * H / 4) return;
  int c0 = (i * 4) & (H - 1);
  const float invN = 1.0f / NN;
  float4 v = b4_to_f4(((const uint2*)Xb)[i]);
  float4 y;
  {
    float m = stats[c0] * invN;
    float var = stats[H + c0] * invN - m * m;
    y.x = g[c0] * (v.x - m) * rsqrtf(var + EPSV) + bt[c0];
  }
  {
    float m = stats[c0 + 1] * invN;
    float var = stats[H + c0 + 1] * invN - m * m;
    y.y = g[c0 + 1] * (v.y - m) * rsqrtf(var + EPSV) + bt[c0 + 1];
  }
  {
    float m = stats[c0 + 2] * invN;
    float var = stats[H + c0 + 2] * invN - m * m;
    y.z = g[c0 + 2] * (v.z - m) * rsqrtf(var + EPSV) + bt[c0 + 2];
  }
  {
    float m = stats[c0 + 3] * invN;
    float var = stats[H + c0 + 3] * invN - m * m;
    y.w = g[c0 + 3] * (v.w - m) * rsqrtf(var + EPSV) + bt[c0 + 3];
  }
  ((uint2*)baseb)[i] = f4_to_b4(y);
  float dv = dinv[i >> 5];
  float4 u = make_float4(y.x * dv, y.y * dv, y.z * dv, y.w * dv);
  out8[i] = f4_to_f8x4(u);
}
__global__ void k_bn_addvn(const float* __restrict__ Y, const float* __restrict__ stats,
                           const float* __restrict__ g, const float* __restrict__ bt,
                           float* vn) {
  int idx = blockIdx.x * blockDim.x + threadIdx.x;
  if (idx >= NG * H) return;
  int c = idx & (H - 1);
  const float invN = 1.0f / NG;
  float m = stats[c] * invN;
  float var = stats[H + c] * invN - m * m;
  float rs = rsqrtf(var + EPSV);
  vn[idx] += fmaxf(g[c] * (Y[idx] - m) * rs + bt[c], 0.f);
}

// ---------------- small matmuls with fused stats ----------------
__global__ void k_mm_vn1(const float* __restrict__ vtsum, const float* __restrict__ vn,
                         const float* __restrict__ W, const float* __restrict__ bias,
                         float* __restrict__ Y, float* __restrict__ gstats) {
  __shared__ float xs[H];
  int r = blockIdx.x, c = threadIdx.x;
  if (c < H) xs[c] = vtsum[r * H + c] + vn[r * H + c];
  __syncthreads();
  float acc = bias[c];
#pragma unroll 16
  for (int k = 0; k < H; k++) acc += xs[k] * W[k * 256 + c];
  Y[r * 256 + c] = acc;
  atomicAdd(&gstats[c], acc);
  atomicAdd(&gstats[256 + c], acc * acc);
}
__global__ void k_mm_vn2(const float* __restrict__ t1raw, const float* __restrict__ stats1,
                         const float* __restrict__ g1, const float* __restrict__ bt1,
                         const float* __restrict__ W, const float* __restrict__ bias,
                         float* __restrict__ Y, float* __restrict__ gstats) {
  __shared__ float xs[256];
  int r = blockIdx.x, c = threadIdx.x;
  const float invG = 1.0f / NG;
#pragma unroll
  for (int hh = 0; hh < 2; hh++) {
    int cc = c + hh * 128;
    float m = stats1[cc] * invG;
    float var = stats1[256 + cc] * invG - m * m;
    float rs = rsqrtf(var + EPSV);
    xs[cc] = fmaxf(g1[cc] * (t1raw[r * 256 + cc] - m) * rs + bt1[cc], 0.f);
  }
  __syncthreads();
  float acc = bias[c];
#pragma unroll 16
  for (int k = 0; k < 256; k++) acc += xs[k] * W[k * H + c];
  Y[r * H + c] = acc;
  atomicAdd(&gstats[c], acc);
  atomicAdd(&gstats[H + c], acc * acc);
}

// ---------------- merged mean pool + head (256 thr: 2-way row-parallel pooling) --------
__global__ void k_pool_head(const unsigned short* __restrict__ hb,
                            const int* __restrict__ gstart, const int* __restrict__ gend,
                            const float* __restrict__ Wout, const float* __restrict__ bout,
                            float* __restrict__ out) {
  __shared__ float part[2][H];
  __shared__ float xs[H];
  int r = blockIdx.x;
  int t = threadIdx.x;
  int c = t & 127, pr = t >> 7;
  int s0 = gstart[r], s1 = gend[r];
  float s = 0.f;
  for (int row = s0 + pr; row < s1; row += 2)
    s += __uint_as_float((uint32_t)hb[(size_t)row * H + c] << 16);
  part[pr][c] = s;
  __syncthreads();
  if (t < H) {
    float cnt = (float)(s1 - s0);
    xs[t] = (part[0][t] + part[1][t]) / fmaxf(cnt, 1.f);
  }
  __syncthreads();
  if (t < OUTC) {
    float acc = bout[t];
#pragma unroll 16
    for (int k = 0; k < H; k++) acc += xs[k] * Wout[k * OUTC + t];
    out[r * OUTC + t] = acc;
  }
}

// ---------------- launch ----------------
extern "C" void kernel_launch(void* const* d_in, const int* in_sizes, int n_in,
                              void* d_out, int out_size, void* d_ws, size_t ws_size,
                              hipStream_t stream) {
  const float* x      = (const float*)d_in[0];
  const int*   ei     = (const int*)d_in[1];
  const int*   e_src  = ei;
  const int*   e_dst  = ei + NE;
  const int*   batch  = (const int*)d_in[2];
  const float* W      = (const float*)d_in[3];
  const float* b      = (const float*)d_in[4];
  const float* gamma  = (const float*)d_in[5];
  const float* beta   = (const float*)d_in[6];
  const float* vn_emb = (const float*)d_in[7];
  const float* W1     = (const float*)d_in[8];
  const float* b1     = (const float*)d_in[9];
  const float* g1     = (const float*)d_in[10];
  const float* bt1    = (const float*)d_in[11];
  const float* W2     = (const float*)d_in[12];
  const float* b2     = (const float*)d_in[13];
  const float* g2     = (const float*)d_in[14];
  const float* bt2    = (const float*)d_in[15];
  const float* Wout   = (const float*)d_in[16];
  const float* bout   = (const float*)d_in[17];
  float* out = (float*)d_out;

  char* p = (char*)d_ws;
  auto alloc = [&](size_t bytes) -> char* {
    char* r = p; p += (bytes + 255) & ~(size_t)255; return r;
  };
  float* hA       = (float*)alloc((size_t)NN * H * 4);        // carved: baseb bf16
  float* hB       = (float*)alloc((size_t)(NN + 1) * H * 4);  // carved: bf0/bf1 (+pad rows)
  float* hC       = (float*)alloc((size_t)NN * H * 2);        // bf16 conv output
  uint32_t* f8a   = (uint32_t*)alloc((size_t)(NN + 1) * H);   // fp8 APPNP ping
  uint32_t* f8b   = (uint32_t*)alloc((size_t)(NN + 1) * H);   // fp8 APPNP pong
  int*   deg      = (int*)alloc((size_t)NN * 4);
  int*   cursor   = (int*)alloc((size_t)NN * 4);
  int*   rowptr   = (int*)alloc((size_t)(NN + 1) * 4);
  int*   gstart   = (int*)alloc(512 * 4);
  int*   gend     = (int*)alloc(512 * 4);
  int*   csr_src  = (int*)alloc((size_t)CSRCAP * 4);
  float* dinv     = (float*)alloc((size_t)NN * 4);
  float* vn       = (float*)alloc((size_t)NG * H * 4);
  float* vtsum0   = (float*)alloc((size_t)NG * H * 4);
  float* t1       = (float*)alloc((size_t)NG * 256 * 4);
  float* t2       = (float*)alloc((size_t)NG * H * 4);
  float* stats    = (float*)alloc(9 * 512 * 4);
  int*   bsum     = (int*)alloc(256 * 4);
  unsigned short* WT = (unsigned short*)alloc((size_t)3 * H * H * 2);
  unsigned short* xb = (unsigned short*)alloc((size_t)(NN + 1) * H * 2);
  float* pstat    = (float*)alloc((size_t)MMB * 256 * 4);

  unsigned short* bf0 = (unsigned short*)hB;                          // NN+1 rows
  unsigned short* bf1 = (unsigned short*)hB + (size_t)(NN + 1) * H;   // NN+1 rows
  unsigned short* baseb = (unsigned short*)hA;
  unsigned short* hCb = (unsigned short*)hC;

  const int B = 256;
  const int gV4   = (NN * H / 4 + B - 1) / B;   // 6250 (covers NE too)
  const int gVN   = (NG * H + B - 1) / B;
  const int gSEG  = (NN + 7) / 8;               // 6250
  const int gPROP = NN / 8;                     // 6250
  const int gNE   = (NE + B - 1) / B;           // 2344 (covers NN too)

  // ---- init + graph preprocessing ----
  k_init<<<(NG * H + B - 1) / B, B, 0, stream>>>(deg, cursor, stats, vtsum0,
                                                 vn_emb, vn, W, WT, xb, bf0, bf1, f8a, f8b);
  k_hist_fill<<<gNE, B, 0, stream>>>(e_dst, deg, batch, gstart, gend);
  k_scan1<<<NB1, 256, 0, stream>>>(deg, bsum, dinv);
  k_scan3<<<NB1, 256, 0, stream>>>(deg, bsum, rowptr, csr_src);
  k_fill_x<<<gV4, B, 0, stream>>>(e_src, e_dst, rowptr, cursor, csr_src, x, dinv, xb);

  float* st[7];
  for (int i = 0; i < 7; i++) st[i] = stats + i * 512;

  // ---- conv layer 0 (full virtual-node MLP: its vn update feeds layer 1) ----
  {
    int j = 1;  // torch negative-index wraparound for i=0
    k_prop_mm<<<MMB, 256, 0, stream>>>(xb, WT, b, hCb, pstat, rowptr, csr_src, dinv);
    k_redstats<<<32, 256, 0, stream>>>(pstat, st[0]);
    k_bn_vn2<<<gSEG, H, 0, stream>>>(hCb, st[0], gamma, beta, vn, batch, dinv, bf1, vtsum0);
    k_mm_vn1<<<NG, 256, 0, stream>>>(vtsum0, vn, W1 + (size_t)j * H * 256, b1 + j * 256, t1, st[1]);
    k_mm_vn2<<<NG, 128, 0, stream>>>(t1, st[1], g1 + j * 256, bt1 + j * 256,
                                     W2 + (size_t)j * 256 * H, b2 + j * H, t2, st[2]);
    k_bn_addvn<<<gVN, B, 0, stream>>>(t2, st[2], g2 + j * H, bt2 + j * H, vn);
  }

  // ---- conv layer 1 (vn update after this layer is DEAD CODE in the reference:
  //      vn is never read again -> skip the MLP and the vt segment-sum) ----
  k_prop_mm<<<MMB, 256, 0, stream>>>(bf1, WT + (size_t)H * H, b + H, hCb, pstat,
                                     rowptr, csr_src, dinv);
  k_redstats<<<32, 256, 0, stream>>>(pstat, st[3]);
  k_bn_vn2<<<gSEG, H, 0, stream>>>(hCb, st[3], gamma + H, beta + H, vn, batch, dinv,
                                   bf0, nullptr);

  // ---- last conv layer: fused prop+mm (bf16 Y), BN -> baseb bf16 + u0 fp8 ----
  k_prop_mm<<<MMB, 256, 0, stream>>>(bf0, WT + (size_t)2 * H * H, b + 2 * H, hCb, pstat,
                                     rowptr, csr_src, dinv);
  k_redstats<<<32, 256, 0, stream>>>(pstat, st[6]);
  k_bn_plain_b<<<gV4, B, 0, stream>>>(hCb, st[6], gamma + 2 * H, beta + 2 * H, dinv, baseb, f8a);

  // ---- APPNP (4 props, fp8 iterate, bf16 base; final -> bf16 h in bf0) ----
  k_prop_f8<<<gPROP, 256, 0, stream>>>(f8a, baseb, f8b, nullptr, rowptr, csr_src, dinv);
  k_prop_f8<<<gPROP, 256, 0, stream>>>(f8b, baseb, f8a, nullptr, rowptr, csr_src, dinv);
  k_prop_f8<<<gPROP, 256, 0, stream>>>(f8a, baseb, f8b, nullptr, rowptr, csr_src, dinv);
  k_prop_f8<<<gPROP, 256, 0, stream>>>(f8b, baseb, nullptr, bf0, rowptr, csr_src, dinv);

  // ---- merged mean pool + head ----
  k_pool_head<<<NG, 256, 0, stream>>>(bf0, gstart, gend, Wout, bout, out);
}